// Round 9
// baseline (296.403 us; speedup 1.0000x reference)
//
#include <hip/hip_runtime.h>

#define NHID 256
#define NFEAT 512

using short8  = __attribute__((ext_vector_type(8))) short;
using float8  = __attribute__((ext_vector_type(8))) float;
using f32x4   = __attribute__((ext_vector_type(4))) float;

__device__ __forceinline__ float b2f(unsigned short u) {
    union { float f; unsigned v; } c;
    c.v = ((unsigned)u) << 16;
    return c.f;
}
__device__ __forceinline__ unsigned short f2b(float f) {
    union { float f; unsigned u; } c;
    c.f = f;
    unsigned r = c.u + 0x7fffu + ((c.u >> 16) & 1u);  // RNE
    return (unsigned short)(r >> 16);
}
__device__ __forceinline__ unsigned short f2h(float f) {
    union { _Float16 h; unsigned short u; } c;
    c.h = (_Float16)f;
    return c.u;
}
__device__ __forceinline__ float h2f(unsigned short u) {
    union { _Float16 h; unsigned short u; } c;
    c.u = u;
    return (float)c.h;
}

// ---------------- W -> MFMA-fragment layout (per-lane order) + cursor zero ----------------
// F[( (t*16 + cb)*64 + lane )*8 + j] = f2b( W[k][n] ), n = cb*16 + (lane&15),
// k = t*32 + (lane>>4)*8 + j.  Wave's b-load becomes one contiguous 1KB dwordx4.
__global__ __launch_bounds__(256) void prep_frags(const float* __restrict__ W1,
                                                  const float* __restrict__ W2,
                                                  unsigned short* __restrict__ F1,
                                                  unsigned short* __restrict__ F2,
                                                  int* __restrict__ cursor, int M) {
    int i = blockIdx.x * blockDim.x + threadIdx.x;
    const int T1 = NFEAT * NHID;   // 131072
    const int T2 = NHID * NHID;    // 65536
    if (i < T1) {
        int j = i & 7, l = (i >> 3) & 63, cb = (i >> 9) & 15, t = i >> 13;
        int n = cb * 16 + (l & 15);
        int k = t * 32 + ((l >> 4) << 3) + j;
        F1[i] = f2b(W1[k * NHID + n]);
    } else if (i < T1 + T2) {
        int i2 = i - T1;
        int j = i2 & 7, l = (i2 >> 3) & 63, cb = (i2 >> 9) & 15, t = i2 >> 13;
        int n = cb * 16 + (l & 15);
        int k = t * 32 + ((l >> 4) << 3) + j;
        F2[i2] = f2b(W2[k * NHID + n]);
    } else {
        int j = i - T1 - T2;
        if (j < M) cursor[j] = 0;
    }
}

// ---------------- GEMM1: C[M,256] = cvt_bf16(x[M,512]) @ W1 ----------------
// 32x256 tile, 4 waves (wave wc owns cols wc*64..), NO LDS, NO barriers.
// A per-lane from global (L1/L2 broadcast across waves), B from fragment buffer (L2-hot).
__global__ __launch_bounds__(256) void gemm1_stream(const float* __restrict__ x,
                                                    const unsigned short* __restrict__ F1,
                                                    unsigned short* __restrict__ C, int M) {
    const int tid = threadIdx.x;
    const int lane = tid & 63;
    const int wc = tid >> 6;
    const int brow = blockIdx.x * 32;
    const int lrow = lane & 15;
    const int lq = lane >> 4;

    int r0 = brow + lrow;      if (r0 >= M) r0 = M - 1;
    int r1 = brow + 16 + lrow; if (r1 >= M) r1 = M - 1;
    const float* a0p = x + (size_t)r0 * NFEAT + lq * 8;
    const float* a1p = x + (size_t)r1 * NFEAT + lq * 8;
    const unsigned short* bp = F1 + (wc * 4 * 64 + lane) * 8;

    f32x4 acc[2][4] = {};

#pragma unroll 4
    for (int t = 0; t < 16; ++t) {
        float8 fa0 = *(const float8*)(a0p + t * 32);
        float8 fa1 = *(const float8*)(a1p + t * 32);
        short8 b0 = *(const short8*)(bp + t * 8192 + 0 * 512);
        short8 b1 = *(const short8*)(bp + t * 8192 + 1 * 512);
        short8 b2 = *(const short8*)(bp + t * 8192 + 2 * 512);
        short8 b3 = *(const short8*)(bp + t * 8192 + 3 * 512);
        short8 a0, a1;
#pragma unroll
        for (int j = 0; j < 8; ++j) { a0[j] = (short)f2b(fa0[j]); a1[j] = (short)f2b(fa1[j]); }
        acc[0][0] = __builtin_amdgcn_mfma_f32_16x16x32_bf16(a0, b0, acc[0][0], 0, 0, 0);
        acc[0][1] = __builtin_amdgcn_mfma_f32_16x16x32_bf16(a0, b1, acc[0][1], 0, 0, 0);
        acc[0][2] = __builtin_amdgcn_mfma_f32_16x16x32_bf16(a0, b2, acc[0][2], 0, 0, 0);
        acc[0][3] = __builtin_amdgcn_mfma_f32_16x16x32_bf16(a0, b3, acc[0][3], 0, 0, 0);
        acc[1][0] = __builtin_amdgcn_mfma_f32_16x16x32_bf16(a1, b0, acc[1][0], 0, 0, 0);
        acc[1][1] = __builtin_amdgcn_mfma_f32_16x16x32_bf16(a1, b1, acc[1][1], 0, 0, 0);
        acc[1][2] = __builtin_amdgcn_mfma_f32_16x16x32_bf16(a1, b2, acc[1][2], 0, 0, 0);
        acc[1][3] = __builtin_amdgcn_mfma_f32_16x16x32_bf16(a1, b3, acc[1][3], 0, 0, 0);
    }

#pragma unroll
    for (int m = 0; m < 2; ++m)
#pragma unroll
        for (int r = 0; r < 4; ++r) {
            int row = brow + m * 16 + (lane >> 4) * 4 + r;
            if (row < M) {
#pragma unroll
                for (int n = 0; n < 4; ++n) {
                    int col = wc * 64 + n * 16 + (lane & 15);
                    C[(size_t)row * NHID + col] = f2b(acc[m][n][r]);
                }
            }
        }
}

// ---------------- GEMM2: C[M,256] = A_bf16[M,256] @ W2 (same structure) ----------------
__global__ __launch_bounds__(256) void gemm2_stream(const unsigned short* __restrict__ A,
                                                    const unsigned short* __restrict__ F2,
                                                    unsigned short* __restrict__ C, int M) {
    const int tid = threadIdx.x;
    const int lane = tid & 63;
    const int wc = tid >> 6;
    const int brow = blockIdx.x * 32;
    const int lrow = lane & 15;
    const int lq = lane >> 4;

    int r0 = brow + lrow;      if (r0 >= M) r0 = M - 1;
    int r1 = brow + 16 + lrow; if (r1 >= M) r1 = M - 1;
    const unsigned short* a0p = A + (size_t)r0 * NHID + lq * 8;
    const unsigned short* a1p = A + (size_t)r1 * NHID + lq * 8;
    const unsigned short* bp = F2 + (wc * 4 * 64 + lane) * 8;

    f32x4 acc[2][4] = {};

#pragma unroll 4
    for (int t = 0; t < 8; ++t) {
        short8 a0 = *(const short8*)(a0p + t * 32);
        short8 a1 = *(const short8*)(a1p + t * 32);
        short8 b0 = *(const short8*)(bp + t * 8192 + 0 * 512);
        short8 b1 = *(const short8*)(bp + t * 8192 + 1 * 512);
        short8 b2 = *(const short8*)(bp + t * 8192 + 2 * 512);
        short8 b3 = *(const short8*)(bp + t * 8192 + 3 * 512);
        acc[0][0] = __builtin_amdgcn_mfma_f32_16x16x32_bf16(a0, b0, acc[0][0], 0, 0, 0);
        acc[0][1] = __builtin_amdgcn_mfma_f32_16x16x32_bf16(a0, b1, acc[0][1], 0, 0, 0);
        acc[0][2] = __builtin_amdgcn_mfma_f32_16x16x32_bf16(a0, b2, acc[0][2], 0, 0, 0);
        acc[0][3] = __builtin_amdgcn_mfma_f32_16x16x32_bf16(a0, b3, acc[0][3], 0, 0, 0);
        acc[1][0] = __builtin_amdgcn_mfma_f32_16x16x32_bf16(a1, b0, acc[1][0], 0, 0, 0);
        acc[1][1] = __builtin_amdgcn_mfma_f32_16x16x32_bf16(a1, b1, acc[1][1], 0, 0, 0);
        acc[1][2] = __builtin_amdgcn_mfma_f32_16x16x32_bf16(a1, b2, acc[1][2], 0, 0, 0);
        acc[1][3] = __builtin_amdgcn_mfma_f32_16x16x32_bf16(a1, b3, acc[1][3], 0, 0, 0);
    }

#pragma unroll
    for (int m = 0; m < 2; ++m)
#pragma unroll
        for (int r = 0; r < 4; ++r) {
            int row = brow + m * 16 + (lane >> 4) * 4 + r;
            if (row < M) {
#pragma unroll
                for (int n = 0; n < 4; ++n) {
                    int col = wc * 64 + n * 16 + (lane & 15);
                    C[(size_t)row * NHID + col] = f2b(acc[m][n][r]);
                }
            }
        }
}

// ---------------- CSR build, XCD-range-partitioned ----------------
__global__ __launch_bounds__(256) void hist_part(const int* __restrict__ dst,
                                                 int* __restrict__ counts,
                                                 int E, int span, int M) {
    const int g = blockIdx.x & 7;
    const int rank = blockIdx.x >> 3;
    const int nrank = gridDim.x >> 3;
    const int lo = g * span;
    const int hi = min(lo + span, M);
    for (int e = rank * blockDim.x + threadIdx.x; e < E; e += nrank * blockDim.x) {
        int d = dst[e];
        if (d >= lo && d < hi) atomicAdd(&counts[d], 1);
    }
}

__global__ __launch_bounds__(1024) void scan_local(const int* __restrict__ counts,
                                                   int* __restrict__ local,
                                                   int* __restrict__ blocksums, int n) {
    __shared__ int s[1024];
    const int tid = threadIdx.x;
    const int idx = blockIdx.x * 1024 + tid;
    int v = (idx < n) ? counts[idx] : 0;
    s[tid] = v;
    __syncthreads();
    for (int off = 1; off < 1024; off <<= 1) {
        int t = (tid >= off) ? s[tid - off] : 0;
        __syncthreads();
        s[tid] += t;
        __syncthreads();
    }
    if (idx < n) local[idx] = s[tid] - v;
    if (tid == 1023) blocksums[blockIdx.x] = s[1023];
}

__global__ __launch_bounds__(1024) void scan_sums(int* __restrict__ blocksums, int nb) {
    __shared__ int s[1024];
    const int tid = threadIdx.x;
    int v = (tid < nb) ? blocksums[tid] : 0;
    s[tid] = v;
    __syncthreads();
    for (int off = 1; off < 1024; off <<= 1) {
        int t = (tid >= off) ? s[tid - off] : 0;
        __syncthreads();
        s[tid] += t;
        __syncthreads();
    }
    if (tid < nb) blocksums[tid] = s[tid] - v;
}

__global__ __launch_bounds__(256) void scan_finalize(int* __restrict__ offsets,
                                                     int* __restrict__ cursor,
                                                     const int* __restrict__ blockoffs,
                                                     int n, int total) {
    int idx = blockIdx.x * blockDim.x + threadIdx.x;
    if (idx < n) {
        int o = offsets[idx] + blockoffs[idx >> 10];
        offsets[idx] = o;
        cursor[idx] = o;
    }
    if (idx == 0) offsets[n] = total;
}

__global__ __launch_bounds__(256) void sort_edges_part(const int* __restrict__ src,
                                                       const int* __restrict__ dst,
                                                       const float* __restrict__ w,
                                                       int* __restrict__ cursor,
                                                       unsigned* __restrict__ pk,
                                                       int E, int span, int M) {
    const int g = blockIdx.x & 7;
    const int rank = blockIdx.x >> 3;
    const int nrank = gridDim.x >> 3;
    const int lo = g * span;
    const int hi = min(lo + span, M);
    for (int e = rank * blockDim.x + threadIdx.x; e < E; e += nrank * blockDim.x) {
        int d = dst[e];
        if (d >= lo && d < hi) {
            int pos = atomicAdd(&cursor[d], 1);
            pk[pos] = ((unsigned)f2h(w[e]) << 16) | (unsigned)src[e];
        }
    }
}

// ---------------- Gather conv layer-1 (bf16 h -> relu -> bf16 z) ----------------
__global__ __launch_bounds__(256) void gather_conv_pk(const unsigned short* __restrict__ h,
                                                      const int* __restrict__ offsets,
                                                      const unsigned* __restrict__ pk,
                                                      unsigned short* __restrict__ z, int N) {
    const int lane = threadIdx.x & 63;
    const int wid = threadIdx.x >> 6;
    const int node = blockIdx.x * 4 + wid;
    if (node >= N) return;
    const int s0 = offsets[node];
    const int s1 = offsets[node + 1];
    float a0 = 0.f, a1 = 0.f, a2 = 0.f, a3 = 0.f;
    int i = s0;
    for (; i + 4 <= s1; i += 4) {
        unsigned qA = pk[i], qB = pk[i + 1], qC = pk[i + 2], qD = pk[i + 3];
        float wA = h2f(qA >> 16), wB = h2f(qB >> 16), wC = h2f(qC >> 16), wD = h2f(qD >> 16);
        ushort4 vA = ((const ushort4*)(h + (size_t)(qA & 0xffffu) * NHID))[lane];
        ushort4 vB = ((const ushort4*)(h + (size_t)(qB & 0xffffu) * NHID))[lane];
        ushort4 vC = ((const ushort4*)(h + (size_t)(qC & 0xffffu) * NHID))[lane];
        ushort4 vD = ((const ushort4*)(h + (size_t)(qD & 0xffffu) * NHID))[lane];
        a0 += wA * b2f(vA.x) + wB * b2f(vB.x) + wC * b2f(vC.x) + wD * b2f(vD.x);
        a1 += wA * b2f(vA.y) + wB * b2f(vB.y) + wC * b2f(vC.y) + wD * b2f(vD.y);
        a2 += wA * b2f(vA.z) + wB * b2f(vB.z) + wC * b2f(vC.z) + wD * b2f(vD.z);
        a3 += wA * b2f(vA.w) + wB * b2f(vB.w) + wC * b2f(vC.w) + wD * b2f(vD.w);
    }
    for (; i < s1; ++i) {
        unsigned q = pk[i];
        float ww = h2f(q >> 16);
        ushort4 v = ((const ushort4*)(h + (size_t)(q & 0xffffu) * NHID))[lane];
        a0 += ww * b2f(v.x);
        a1 += ww * b2f(v.y);
        a2 += ww * b2f(v.z);
        a3 += ww * b2f(v.w);
    }
    a0 = fmaxf(a0, 0.f); a1 = fmaxf(a1, 0.f);
    a2 = fmaxf(a2, 0.f); a3 = fmaxf(a3, 0.f);
    ushort4 o;
    o.x = f2b(a0); o.y = f2b(a1); o.z = f2b(a2); o.w = f2b(a3);
    ((ushort4*)(z + (size_t)node * NHID))[lane] = o;
}

// ---------------- Gather conv layer-2 fused with Wlin projection ----------------
__global__ __launch_bounds__(256) void gather_wlin_pk(const unsigned short* __restrict__ h,
                                                      const int* __restrict__ offsets,
                                                      const unsigned* __restrict__ pk,
                                                      const float* __restrict__ Wlin,
                                                      float2* __restrict__ za,
                                                      float2* __restrict__ zb, int N) {
    const int lane = threadIdx.x & 63;
    const int wid = threadIdx.x >> 6;
    const int node = blockIdx.x * 4 + wid;
    if (node >= N) return;

    float wt[8], wbm[8];
#pragma unroll
    for (int i = 0; i < 8; ++i) {
        wt[i]  = Wlin[(lane * 4) * 2 + i];
        wbm[i] = Wlin[(NHID + lane * 4) * 2 + i];
    }

    const int s0 = offsets[node];
    const int s1 = offsets[node + 1];
    float a0 = 0.f, a1 = 0.f, a2 = 0.f, a3 = 0.f;
    int i = s0;
    for (; i + 4 <= s1; i += 4) {
        unsigned qA = pk[i], qB = pk[i + 1], qC = pk[i + 2], qD = pk[i + 3];
        float wA = h2f(qA >> 16), wB = h2f(qB >> 16), wC = h2f(qC >> 16), wD = h2f(qD >> 16);
        ushort4 vA = ((const ushort4*)(h + (size_t)(qA & 0xffffu) * NHID))[lane];
        ushort4 vB = ((const ushort4*)(h + (size_t)(qB & 0xffffu) * NHID))[lane];
        ushort4 vC = ((const ushort4*)(h + (size_t)(qC & 0xffffu) * NHID))[lane];
        ushort4 vD = ((const ushort4*)(h + (size_t)(qD & 0xffffu) * NHID))[lane];
        a0 += wA * b2f(vA.x) + wB * b2f(vB.x) + wC * b2f(vC.x) + wD * b2f(vD.x);
        a1 += wA * b2f(vA.y) + wB * b2f(vB.y) + wC * b2f(vC.y) + wD * b2f(vD.y);
        a2 += wA * b2f(vA.z) + wB * b2f(vB.z) + wC * b2f(vC.z) + wD * b2f(vD.z);
        a3 += wA * b2f(vA.w) + wB * b2f(vB.w) + wC * b2f(vC.w) + wD * b2f(vD.w);
    }
    for (; i < s1; ++i) {
        unsigned q = pk[i];
        float ww = h2f(q >> 16);
        ushort4 v = ((const ushort4*)(h + (size_t)(q & 0xffffu) * NHID))[lane];
        a0 += ww * b2f(v.x);
        a1 += ww * b2f(v.y);
        a2 += ww * b2f(v.z);
        a3 += ww * b2f(v.w);
    }

    float pa0 = a0 * wt[0] + a1 * wt[2] + a2 * wt[4] + a3 * wt[6];
    float pa1 = a0 * wt[1] + a1 * wt[3] + a2 * wt[5] + a3 * wt[7];
    float pb0 = a0 * wbm[0] + a1 * wbm[2] + a2 * wbm[4] + a3 * wbm[6];
    float pb1 = a0 * wbm[1] + a1 * wbm[3] + a2 * wbm[5] + a3 * wbm[7];
#pragma unroll
    for (int off = 32; off > 0; off >>= 1) {
        pa0 += __shfl_down(pa0, off);
        pa1 += __shfl_down(pa1, off);
        pb0 += __shfl_down(pb0, off);
        pb1 += __shfl_down(pb1, off);
    }
    if (lane == 0) {
        za[node] = {pa0, pa1};
        zb[node] = {pb0, pb1};
    }
}

// ---------------- Decode: out[p] = za[ps[p]] + zb[pd[p]] ----------------
__global__ __launch_bounds__(256) void decode_pairs(const float2* __restrict__ za,
                                                    const float2* __restrict__ zb,
                                                    const int* __restrict__ ps,
                                                    const int* __restrict__ pd,
                                                    float2* __restrict__ out, int P) {
    int p = blockIdx.x * blockDim.x + threadIdx.x;
    if (p < P) {
        float2 va = za[ps[p]];
        float2 vb = zb[pd[p]];
        out[p] = {va.x + vb.x, va.y + vb.y};
    }
}

// ================= fp32 fallback path (ws too small or M > 65535) =================
template <bool RELU>
__global__ __launch_bounds__(256) void gemm_tiled(const float* __restrict__ A,
                                                  const float* __restrict__ B,
                                                  float* __restrict__ C,
                                                  int M, int N, int K) {
    __shared__ float As[16][65];
    __shared__ float Bs[16][64];
    const int block_row = blockIdx.x * 64;
    const int block_col = blockIdx.y * 64;
    const int tid = threadIdx.x;
    const int tx = tid & 15;
    const int ty = tid >> 4;
    float c[4][4] = {};
    for (int k0 = 0; k0 < K; k0 += 16) {
#pragma unroll
        for (int i = 0; i < 4; ++i) {
            int idx = tid + i * 256;
            int kk = idx & 15;
            int m = idx >> 4;
            int row = block_row + m;
            float v = 0.f;
            if (row < M) v = A[(long)row * K + k0 + kk];
            if (RELU) v = fmaxf(v, 0.f);
            As[kk][m] = v;
        }
#pragma unroll
        for (int i = 0; i < 4; ++i) {
            int idx = tid + i * 256;
            int n = idx & 63;
            int kk = idx >> 6;
            Bs[kk][n] = B[(long)(k0 + kk) * N + block_col + n];
        }
        __syncthreads();
#pragma unroll
        for (int kk = 0; kk < 16; ++kk) {
            float a[4], b[4];
#pragma unroll
            for (int i = 0; i < 4; ++i) a[i] = As[kk][ty * 4 + i];
#pragma unroll
            for (int j = 0; j < 4; ++j) b[j] = Bs[kk][tx * 4 + j];
#pragma unroll
            for (int i = 0; i < 4; ++i)
#pragma unroll
                for (int j = 0; j < 4; ++j) c[i][j] += a[i] * b[j];
        }
        __syncthreads();
    }
#pragma unroll
    for (int i = 0; i < 4; ++i) {
        int row = block_row + ty * 4 + i;
        if (row < M) {
            float* cp = C + (long)row * N + block_col + tx * 4;
#pragma unroll
            for (int j = 0; j < 4; ++j) cp[j] = c[i][j];
        }
    }
}

__global__ __launch_bounds__(256) void scatter_conv(const float* __restrict__ h,
                                                    const int* __restrict__ src,
                                                    const int* __restrict__ dst,
                                                    const float* __restrict__ w,
                                                    float* __restrict__ z, int E) {
    const int lane = threadIdx.x & 63;
    const int wid = threadIdx.x >> 6;
    const int nwaves = (gridDim.x * blockDim.x) >> 6;
    for (int e = blockIdx.x * 4 + wid; e < E; e += nwaves) {
        int s = src[e];
        int d = dst[e];
        float ww = w[e];
        float4 v = ((const float4*)(h + (long)s * NHID))[lane];
        float* zp = z + (long)d * NHID + lane * 4;
        atomicAdd(zp + 0, ww * v.x);
        atomicAdd(zp + 1, ww * v.y);
        atomicAdd(zp + 2, ww * v.z);
        atomicAdd(zp + 3, ww * v.w);
    }
}

__global__ __launch_bounds__(256) void decode_f(const float* __restrict__ z,
                                                const int* __restrict__ ps,
                                                const int* __restrict__ pd,
                                                const float* __restrict__ Wlin,
                                                float* __restrict__ out, int P) {
    const int lane = threadIdx.x & 63;
    const int wid = threadIdx.x >> 6;
    const int nwaves = (gridDim.x * blockDim.x) >> 6;
    float wa[8], wb[8];
#pragma unroll
    for (int i = 0; i < 8; ++i) {
        wa[i] = Wlin[(lane * 4) * 2 + i];
        wb[i] = Wlin[(NHID + lane * 4) * 2 + i];
    }
    for (int p = blockIdx.x * 4 + wid; p < P; p += nwaves) {
        int a = ps[p];
        int b = pd[p];
        float4 va = ((const float4*)(z + (long)a * NHID))[lane];
        float4 vb = ((const float4*)(z + (long)b * NHID))[lane];
        float acc0 = va.x * wa[0] + va.y * wa[2] + va.z * wa[4] + va.w * wa[6]
                   + vb.x * wb[0] + vb.y * wb[2] + vb.z * wb[4] + vb.w * wb[6];
        float acc1 = va.x * wa[1] + va.y * wa[3] + va.z * wa[5] + va.w * wa[7]
                   + vb.x * wb[1] + vb.y * wb[3] + vb.z * wb[5] + vb.w * wb[7];
#pragma unroll
        for (int off = 32; off > 0; off >>= 1) {
            acc0 += __shfl_down(acc0, off);
            acc1 += __shfl_down(acc1, off);
        }
        if (lane == 0) {
            out[(long)p * 2 + 0] = acc0;
            out[(long)p * 2 + 1] = acc1;
        }
    }
}

extern "C" void kernel_launch(void* const* d_in, const int* in_sizes, int n_in,
                              void* d_out, int out_size, void* d_ws, size_t ws_size,
                              hipStream_t stream) {
    (void)n_in; (void)out_size;
    const float* x    = (const float*)d_in[0];   // [M, 512]
    const int*   ei   = (const int*)d_in[1];     // [2, E]
    const float* ew   = (const float*)d_in[2];   // [E]
    const int*   pei  = (const int*)d_in[3];     // [2, P]
    const float* W1   = (const float*)d_in[4];   // [512, 256]
    const float* W2   = (const float*)d_in[5];   // [256, 256]
    const float* Wlin = (const float*)d_in[6];   // [512, 2]
    float* out = (float*)d_out;                  // [P, 2]

    const int E = in_sizes[2];
    const int P = in_sizes[3] / 2;
    const int M = in_sizes[0] / NFEAT;

    dim3 blk(256);
    const int* src = ei;
    const int* dst = ei + E;

    // workspace layout (bf16 path)
    unsigned short* hA = (unsigned short*)d_ws;               // [M,256] bf16
    unsigned short* hB = hA + (size_t)M * NHID;               // [M,256] bf16
    int* offsets = (int*)(hB + (size_t)M * NHID);             // [M+1]
    int* cursor  = offsets + (M + 1);                          // [M]
    unsigned* pk = (unsigned*)(cursor + M);                    // [E] packed (f16 w | u16 src)
    int* blocksums = (int*)(pk + E);                           // [1024]
    float2* za = (float2*)(blocksums + 1024);                  // [M]
    float2* zb = za + M;                                       // [M]
    const size_t need = 2 * (size_t)M * NHID * 2 + ((size_t)2 * M + 1) * 4
                      + (size_t)E * 4 + 1024 * 4 + (size_t)M * 2 * 8;

    if (ws_size >= need && M <= 65535) {
        unsigned short* F1 = (unsigned short*)d_out;          // [131072] bf16 frag (256 KB)
        unsigned short* F2 = F1 + (size_t)NHID * NFEAT;       // [65536] bf16 frag (128 KB)

        const int zt = NFEAT * NHID + NHID * NHID + M;
        prep_frags<<<(zt + 255) / 256, blk, 0, stream>>>(W1, W2, F1, F2, cursor, M);

        // ---- CSR build (XCD-range-partitioned hist + sort) ----
        const int span = (M + 7) / 8;
        const int nb = (M + 1023) / 1024;
        hist_part<<<2048, blk, 0, stream>>>(dst, cursor, E, span, M);
        scan_local<<<nb, 1024, 0, stream>>>(cursor, offsets, blocksums, M);
        scan_sums<<<1, 1024, 0, stream>>>(blocksums, nb);
        scan_finalize<<<(M + 255) / 256, blk, 0, stream>>>(offsets, cursor, blocksums, M, E);
        sort_edges_part<<<2048, blk, 0, stream>>>(src, dst, ew, cursor, pk, E, span, M);

        // ---- Layer 1: hA = cvt(x) @ W1 ----
        const int g = (M + 31) / 32;
        gemm1_stream<<<g, blk, 0, stream>>>(x, F1, hA, M);
        gather_conv_pk<<<(M + 3) / 4, blk, 0, stream>>>(hA, offsets, pk, hB, M);
        // ---- Layer 2 + fused Wlin projection ----
        gemm2_stream<<<g, blk, 0, stream>>>(hB, F2, hA, M);
        gather_wlin_pk<<<(M + 3) / 4, blk, 0, stream>>>(hA, offsets, pk, Wlin, za, zb, M);
        // ---- Decode ----
        decode_pairs<<<(P + 255) / 256, blk, 0, stream>>>(za, zb, pei, pei + P, (float2*)out, P);
    } else {
        // fp32 atomic fallback
        float* bufA = (float*)d_ws;
        float* bufB = bufA + (size_t)M * NHID;
        const size_t zbytes = (size_t)M * NHID * sizeof(float);
        dim3 gemm_grid((M + 63) / 64, NHID / 64);
        gemm_tiled<false><<<gemm_grid, blk, 0, stream>>>(x, W1, bufA, M, NHID, NFEAT);
        hipMemsetAsync(bufB, 0, zbytes, stream);
        scatter_conv<<<2048, blk, 0, stream>>>(bufA, src, dst, ew, bufB, E);
        gemm_tiled<true><<<gemm_grid, blk, 0, stream>>>(bufB, W2, bufA, M, NHID, NHID);
        hipMemsetAsync(bufB, 0, zbytes, stream);
        scatter_conv<<<2048, blk, 0, stream>>>(bufA, src, dst, ew, bufB, E);
        decode_f<<<(P + 3) / 4, blk, 0, stream>>>(bufB, pei, pei + P, Wlin, out, P);
    }
}

// Round 10
// 262.098 us; speedup vs baseline: 1.1309x; 1.1309x over previous
//
#include <hip/hip_runtime.h>

#define NHID 256
#define NFEAT 512

using short8  = __attribute__((ext_vector_type(8))) short;
using float8  = __attribute__((ext_vector_type(8))) float;
using f32x4   = __attribute__((ext_vector_type(4))) float;

__device__ __forceinline__ float b2f(unsigned short u) {
    union { float f; unsigned v; } c;
    c.v = ((unsigned)u) << 16;
    return c.f;
}
__device__ __forceinline__ unsigned short f2b(float f) {
    union { float f; unsigned u; } c;
    c.f = f;
    unsigned r = c.u + 0x7fffu + ((c.u >> 16) & 1u);  // RNE
    return (unsigned short)(r >> 16);
}
__device__ __forceinline__ unsigned short f2h(float f) {
    union { _Float16 h; unsigned short u; } c;
    c.h = (_Float16)f;
    return c.u;
}
__device__ __forceinline__ float h2f(unsigned short u) {
    union { _Float16 h; unsigned short u; } c;
    c.u = u;
    return (float)c.h;
}

// async global->LDS, 16 B per lane; lds base wave-uniform, gsrc per-lane.
__device__ __forceinline__ void gload16(const void* gsrc, void* lds) {
    __builtin_amdgcn_global_load_lds((const __attribute__((address_space(1))) unsigned int*)gsrc,
                                     (__attribute__((address_space(3))) unsigned int*)lds,
                                     16, 0, 0);
}

// ---------------- W -> MFMA-fragment layout (per-lane order) + cursor zero ----------------
// F[((t*16+cb)*64+lane)*8 + j] = f2b(W[k][n]), n = cb*16+(lane&15), k = t*32+(lane>>4)*8+j.
// Per K-step t the 16 KB chunk F[t*8192..] is exactly the LDS image (contiguous).
__global__ __launch_bounds__(256) void prep_frags(const float* __restrict__ W1,
                                                  const float* __restrict__ W2,
                                                  unsigned short* __restrict__ F1,
                                                  unsigned short* __restrict__ F2,
                                                  int* __restrict__ cursor, int M) {
    int i = blockIdx.x * blockDim.x + threadIdx.x;
    const int T1 = NFEAT * NHID;   // 131072
    const int T2 = NHID * NHID;    // 65536
    if (i < T1) {
        int j = i & 7, l = (i >> 3) & 63, cb = (i >> 9) & 15, t = i >> 13;
        int n = cb * 16 + (l & 15);
        int k = t * 32 + ((l >> 4) << 3) + j;
        F1[i] = f2b(W1[k * NHID + n]);
    } else if (i < T1 + T2) {
        int i2 = i - T1;
        int j = i2 & 7, l = (i2 >> 3) & 63, cb = (i2 >> 9) & 15, t = i2 >> 13;
        int n = cb * 16 + (l & 15);
        int k = t * 32 + ((l >> 4) << 3) + j;
        F2[i2] = f2b(W2[k * NHID + n]);
    } else {
        int j = i - T1 - T2;
        if (j < M) cursor[j] = 0;
    }
}

// ---------------- GEMM1: C[M,256] = cvt_bf16(x[M,512]) @ W1 ----------------
// 64x256 tile, 4 waves. B staged via gload_lds into fragment-linear LDS (conflict-free
// b-reads); A reg-staged fp32->bf16 into padded LDS. Double-buffered, 1 barrier/K-step.
__global__ __launch_bounds__(256) void gemm1_tile(const float* __restrict__ x,
                                                  const unsigned short* __restrict__ F1,
                                                  unsigned short* __restrict__ C, int M) {
    constexpr int LDA = 40;                    // padded bf16 row -> 2-way max
    __shared__ unsigned short As[2][64 * LDA]; // 5 KB / buf
    __shared__ unsigned short Bs[2][8192];     // 16 KB / buf (fragment order)
    const int tid = threadIdx.x;
    const int lane = tid & 63;
    const int wc = tid >> 6;
    const int brow = blockIdx.x * 64;
    const int lrow = lane & 15;
    const int lk = (lane >> 4) * 8;

    // A staging: thread -> row tid>>2, k chunk (tid&3)*8 (float8 = 32 B)
    const int arow = tid >> 2;
    const int akp = (tid & 3) * 8;
    int agrow = brow + arow; if (agrow >= M) agrow = M - 1;
    const float* aptr = x + (size_t)agrow * NFEAT + akp;

    // B staging: wave wc stages its own 4 chunks j = wc*4+c (512 shorts each)
    const unsigned short* bsrc = F1 + (wc * 4) * 512 + lane * 8;

    f32x4 acc[4][4] = {};
    const int nt = NFEAT / 32;   // 16

    // prologue: stage tile 0
    {
#pragma unroll
        for (int c = 0; c < 4; ++c)
            gload16(bsrc + c * 512, &Bs[0][(wc * 4 + c) * 512]);
        float8 t0 = *(const float8*)aptr;
        short8 v;
#pragma unroll
        for (int j = 0; j < 8; ++j) v[j] = (short)f2b(t0[j]);
        *(short8*)(&As[0][arow * LDA + akp]) = v;
    }
    __syncthreads();

    int p = 0;
    for (int t = 0; t < nt; ++t) {
        float8 pa = {};
        if (t + 1 < nt) {
            const unsigned short* bs = bsrc + (t + 1) * 8192;
#pragma unroll
            for (int c = 0; c < 4; ++c)
                gload16(bs + c * 512, &Bs[p ^ 1][(wc * 4 + c) * 512]);
            pa = *(const float8*)(aptr + (t + 1) * 32);
        }
        short8 a[4], b[4];
#pragma unroll
        for (int m = 0; m < 4; ++m)
            a[m] = *(const short8*)(&As[p][(m * 16 + lrow) * LDA + lk]);
#pragma unroll
        for (int n = 0; n < 4; ++n)
            b[n] = *(const short8*)(&Bs[p][(wc * 4 + n) * 512 + lane * 8]);
#pragma unroll
        for (int m = 0; m < 4; ++m)
#pragma unroll
            for (int n = 0; n < 4; ++n)
                acc[m][n] = __builtin_amdgcn_mfma_f32_16x16x32_bf16(a[m], b[n], acc[m][n], 0, 0, 0);
        if (t + 1 < nt) {
            short8 v;
#pragma unroll
            for (int j = 0; j < 8; ++j) v[j] = (short)f2b(pa[j]);
            *(short8*)(&As[p ^ 1][arow * LDA + akp]) = v;
        }
        __syncthreads();
        p ^= 1;
    }

#pragma unroll
    for (int m = 0; m < 4; ++m)
#pragma unroll
        for (int r = 0; r < 4; ++r) {
            int row = brow + m * 16 + (lane >> 4) * 4 + r;
            if (row < M) {
#pragma unroll
                for (int n = 0; n < 4; ++n) {
                    int col = wc * 64 + n * 16 + (lane & 15);
                    C[(size_t)row * NHID + col] = f2b(acc[m][n][r]);
                }
            }
        }
}

// ---------------- GEMM2: C[M,256] = A_bf16[M,256] @ W2 (same structure, bf16 A) ----------------
__global__ __launch_bounds__(256) void gemm2_tile(const unsigned short* __restrict__ A,
                                                  const unsigned short* __restrict__ F2,
                                                  unsigned short* __restrict__ C, int M) {
    constexpr int LDA = 40;
    __shared__ unsigned short As[2][64 * LDA];
    __shared__ unsigned short Bs[2][8192];
    const int tid = threadIdx.x;
    const int lane = tid & 63;
    const int wc = tid >> 6;
    const int brow = blockIdx.x * 64;
    const int lrow = lane & 15;
    const int lk = (lane >> 4) * 8;

    // A staging: thread -> row tid>>2, k chunk (tid&3)*8 (short8 = 16 B)
    const int arow = tid >> 2;
    const int akp = (tid & 3) * 8;
    int agrow = brow + arow; if (agrow >= M) agrow = M - 1;
    const unsigned short* aptr = A + (size_t)agrow * NHID + akp;

    const unsigned short* bsrc = F2 + (wc * 4) * 512 + lane * 8;

    f32x4 acc[4][4] = {};
    const int nt = NHID / 32;   // 8

    {
#pragma unroll
        for (int c = 0; c < 4; ++c)
            gload16(bsrc + c * 512, &Bs[0][(wc * 4 + c) * 512]);
        *(short8*)(&As[0][arow * LDA + akp]) = *(const short8*)aptr;
    }
    __syncthreads();

    int p = 0;
    for (int t = 0; t < nt; ++t) {
        short8 pa = {};
        if (t + 1 < nt) {
            const unsigned short* bs = bsrc + (t + 1) * 8192;
#pragma unroll
            for (int c = 0; c < 4; ++c)
                gload16(bs + c * 512, &Bs[p ^ 1][(wc * 4 + c) * 512]);
            pa = *(const short8*)(aptr + (t + 1) * 32);
        }
        short8 a[4], b[4];
#pragma unroll
        for (int m = 0; m < 4; ++m)
            a[m] = *(const short8*)(&As[p][(m * 16 + lrow) * LDA + lk]);
#pragma unroll
        for (int n = 0; n < 4; ++n)
            b[n] = *(const short8*)(&Bs[p][(wc * 4 + n) * 512 + lane * 8]);
#pragma unroll
        for (int m = 0; m < 4; ++m)
#pragma unroll
            for (int n = 0; n < 4; ++n)
                acc[m][n] = __builtin_amdgcn_mfma_f32_16x16x32_bf16(a[m], b[n], acc[m][n], 0, 0, 0);
        if (t + 1 < nt)
            *(short8*)(&As[p ^ 1][arow * LDA + akp]) = pa;
        __syncthreads();
        p ^= 1;
    }

#pragma unroll
    for (int m = 0; m < 4; ++m)
#pragma unroll
        for (int r = 0; r < 4; ++r) {
            int row = brow + m * 16 + (lane >> 4) * 4 + r;
            if (row < M) {
#pragma unroll
                for (int n = 0; n < 4; ++n) {
                    int col = wc * 64 + n * 16 + (lane & 15);
                    C[(size_t)row * NHID + col] = f2b(acc[m][n][r]);
                }
            }
        }
}

// ---------------- CSR build, XCD-range-partitioned ----------------
__global__ __launch_bounds__(256) void hist_part(const int* __restrict__ dst,
                                                 int* __restrict__ counts,
                                                 int E, int span, int M) {
    const int g = blockIdx.x & 7;
    const int rank = blockIdx.x >> 3;
    const int nrank = gridDim.x >> 3;
    const int lo = g * span;
    const int hi = min(lo + span, M);
    for (int e = rank * blockDim.x + threadIdx.x; e < E; e += nrank * blockDim.x) {
        int d = dst[e];
        if (d >= lo && d < hi) atomicAdd(&counts[d], 1);
    }
}

__global__ __launch_bounds__(1024) void scan_local(const int* __restrict__ counts,
                                                   int* __restrict__ local,
                                                   int* __restrict__ blocksums, int n) {
    __shared__ int s[1024];
    const int tid = threadIdx.x;
    const int idx = blockIdx.x * 1024 + tid;
    int v = (idx < n) ? counts[idx] : 0;
    s[tid] = v;
    __syncthreads();
    for (int off = 1; off < 1024; off <<= 1) {
        int t = (tid >= off) ? s[tid - off] : 0;
        __syncthreads();
        s[tid] += t;
        __syncthreads();
    }
    if (idx < n) local[idx] = s[tid] - v;
    if (tid == 1023) blocksums[blockIdx.x] = s[1023];
}

__global__ __launch_bounds__(1024) void scan_sums(int* __restrict__ blocksums, int nb) {
    __shared__ int s[1024];
    const int tid = threadIdx.x;
    int v = (tid < nb) ? blocksums[tid] : 0;
    s[tid] = v;
    __syncthreads();
    for (int off = 1; off < 1024; off <<= 1) {
        int t = (tid >= off) ? s[tid - off] : 0;
        __syncthreads();
        s[tid] += t;
        __syncthreads();
    }
    if (tid < nb) blocksums[tid] = s[tid] - v;
}

__global__ __launch_bounds__(256) void scan_finalize(int* __restrict__ offsets,
                                                     int* __restrict__ cursor,
                                                     const int* __restrict__ blockoffs,
                                                     int n, int total) {
    int idx = blockIdx.x * blockDim.x + threadIdx.x;
    if (idx < n) {
        int o = offsets[idx] + blockoffs[idx >> 10];
        offsets[idx] = o;
        cursor[idx] = o;
    }
    if (idx == 0) offsets[n] = total;
}

__global__ __launch_bounds__(256) void sort_edges_part(const int* __restrict__ src,
                                                       const int* __restrict__ dst,
                                                       const float* __restrict__ w,
                                                       int* __restrict__ cursor,
                                                       unsigned* __restrict__ pk,
                                                       int E, int span, int M) {
    const int g = blockIdx.x & 7;
    const int rank = blockIdx.x >> 3;
    const int nrank = gridDim.x >> 3;
    const int lo = g * span;
    const int hi = min(lo + span, M);
    for (int e = rank * blockDim.x + threadIdx.x; e < E; e += nrank * blockDim.x) {
        int d = dst[e];
        if (d >= lo && d < hi) {
            int pos = atomicAdd(&cursor[d], 1);
            pk[pos] = ((unsigned)f2h(w[e]) << 16) | (unsigned)src[e];
        }
    }
}

// ---------------- Gather conv layer-1 (bf16 h -> relu -> bf16 z) ----------------
__global__ __launch_bounds__(256) void gather_conv_pk(const unsigned short* __restrict__ h,
                                                      const int* __restrict__ offsets,
                                                      const unsigned* __restrict__ pk,
                                                      unsigned short* __restrict__ z, int N) {
    const int lane = threadIdx.x & 63;
    const int wid = threadIdx.x >> 6;
    const int node = blockIdx.x * 4 + wid;
    if (node >= N) return;
    const int s0 = offsets[node];
    const int s1 = offsets[node + 1];
    float a0 = 0.f, a1 = 0.f, a2 = 0.f, a3 = 0.f;
    int i = s0;
    for (; i + 4 <= s1; i += 4) {
        unsigned qA = pk[i], qB = pk[i + 1], qC = pk[i + 2], qD = pk[i + 3];
        float wA = h2f(qA >> 16), wB = h2f(qB >> 16), wC = h2f(qC >> 16), wD = h2f(qD >> 16);
        ushort4 vA = ((const ushort4*)(h + (size_t)(qA & 0xffffu) * NHID))[lane];
        ushort4 vB = ((const ushort4*)(h + (size_t)(qB & 0xffffu) * NHID))[lane];
        ushort4 vC = ((const ushort4*)(h + (size_t)(qC & 0xffffu) * NHID))[lane];
        ushort4 vD = ((const ushort4*)(h + (size_t)(qD & 0xffffu) * NHID))[lane];
        a0 += wA * b2f(vA.x) + wB * b2f(vB.x) + wC * b2f(vC.x) + wD * b2f(vD.x);
        a1 += wA * b2f(vA.y) + wB * b2f(vB.y) + wC * b2f(vC.y) + wD * b2f(vD.y);
        a2 += wA * b2f(vA.z) + wB * b2f(vB.z) + wC * b2f(vC.z) + wD * b2f(vD.z);
        a3 += wA * b2f(vA.w) + wB * b2f(vB.w) + wC * b2f(vC.w) + wD * b2f(vD.w);
    }
    for (; i < s1; ++i) {
        unsigned q = pk[i];
        float ww = h2f(q >> 16);
        ushort4 v = ((const ushort4*)(h + (size_t)(q & 0xffffu) * NHID))[lane];
        a0 += ww * b2f(v.x);
        a1 += ww * b2f(v.y);
        a2 += ww * b2f(v.z);
        a3 += ww * b2f(v.w);
    }
    a0 = fmaxf(a0, 0.f); a1 = fmaxf(a1, 0.f);
    a2 = fmaxf(a2, 0.f); a3 = fmaxf(a3, 0.f);
    ushort4 o;
    o.x = f2b(a0); o.y = f2b(a1); o.z = f2b(a2); o.w = f2b(a3);
    ((ushort4*)(z + (size_t)node * NHID))[lane] = o;
}

// ---------------- Gather conv layer-2 fused with Wlin projection ----------------
__global__ __launch_bounds__(256) void gather_wlin_pk(const unsigned short* __restrict__ h,
                                                      const int* __restrict__ offsets,
                                                      const unsigned* __restrict__ pk,
                                                      const float* __restrict__ Wlin,
                                                      float2* __restrict__ za,
                                                      float2* __restrict__ zb, int N) {
    const int lane = threadIdx.x & 63;
    const int wid = threadIdx.x >> 6;
    const int node = blockIdx.x * 4 + wid;
    if (node >= N) return;

    float wt[8], wbm[8];
#pragma unroll
    for (int i = 0; i < 8; ++i) {
        wt[i]  = Wlin[(lane * 4) * 2 + i];
        wbm[i] = Wlin[(NHID + lane * 4) * 2 + i];
    }

    const int s0 = offsets[node];
    const int s1 = offsets[node + 1];
    float a0 = 0.f, a1 = 0.f, a2 = 0.f, a3 = 0.f;
    int i = s0;
    for (; i + 4 <= s1; i += 4) {
        unsigned qA = pk[i], qB = pk[i + 1], qC = pk[i + 2], qD = pk[i + 3];
        float wA = h2f(qA >> 16), wB = h2f(qB >> 16), wC = h2f(qC >> 16), wD = h2f(qD >> 16);
        ushort4 vA = ((const ushort4*)(h + (size_t)(qA & 0xffffu) * NHID))[lane];
        ushort4 vB = ((const ushort4*)(h + (size_t)(qB & 0xffffu) * NHID))[lane];
        ushort4 vC = ((const ushort4*)(h + (size_t)(qC & 0xffffu) * NHID))[lane];
        ushort4 vD = ((const ushort4*)(h + (size_t)(qD & 0xffffu) * NHID))[lane];
        a0 += wA * b2f(vA.x) + wB * b2f(vB.x) + wC * b2f(vC.x) + wD * b2f(vD.x);
        a1 += wA * b2f(vA.y) + wB * b2f(vB.y) + wC * b2f(vC.y) + wD * b2f(vD.y);
        a2 += wA * b2f(vA.z) + wB * b2f(vB.z) + wC * b2f(vC.z) + wD * b2f(vD.z);
        a3 += wA * b2f(vA.w) + wB * b2f(vB.w) + wC * b2f(vC.w) + wD * b2f(vD.w);
    }
    for (; i < s1; ++i) {
        unsigned q = pk[i];
        float ww = h2f(q >> 16);
        ushort4 v = ((const ushort4*)(h + (size_t)(q & 0xffffu) * NHID))[lane];
        a0 += ww * b2f(v.x);
        a1 += ww * b2f(v.y);
        a2 += ww * b2f(v.z);
        a3 += ww * b2f(v.w);
    }

    float pa0 = a0 * wt[0] + a1 * wt[2] + a2 * wt[4] + a3 * wt[6];
    float pa1 = a0 * wt[1] + a1 * wt[3] + a2 * wt[5] + a3 * wt[7];
    float pb0 = a0 * wbm[0] + a1 * wbm[2] + a2 * wbm[4] + a3 * wbm[6];
    float pb1 = a0 * wbm[1] + a1 * wbm[3] + a2 * wbm[5] + a3 * wbm[7];
#pragma unroll
    for (int off = 32; off > 0; off >>= 1) {
        pa0 += __shfl_down(pa0, off);
        pa1 += __shfl_down(pa1, off);
        pb0 += __shfl_down(pb0, off);
        pb1 += __shfl_down(pb1, off);
    }
    if (lane == 0) {
        za[node] = {pa0, pa1};
        zb[node] = {pb0, pb1};
    }
}

// ---------------- Decode: out[p] = za[ps[p]] + zb[pd[p]] ----------------
__global__ __launch_bounds__(256) void decode_pairs(const float2* __restrict__ za,
                                                    const float2* __restrict__ zb,
                                                    const int* __restrict__ ps,
                                                    const int* __restrict__ pd,
                                                    float2* __restrict__ out, int P) {
    int p = blockIdx.x * blockDim.x + threadIdx.x;
    if (p < P) {
        float2 va = za[ps[p]];
        float2 vb = zb[pd[p]];
        out[p] = {va.x + vb.x, va.y + vb.y};
    }
}

// ================= fp32 fallback path (ws too small or M > 65535) =================
template <bool RELU>
__global__ __launch_bounds__(256) void gemm_tiled(const float* __restrict__ A,
                                                  const float* __restrict__ B,
                                                  float* __restrict__ C,
                                                  int M, int N, int K) {
    __shared__ float As[16][65];
    __shared__ float Bs[16][64];
    const int block_row = blockIdx.x * 64;
    const int block_col = blockIdx.y * 64;
    const int tid = threadIdx.x;
    const int tx = tid & 15;
    const int ty = tid >> 4;
    float c[4][4] = {};
    for (int k0 = 0; k0 < K; k0 += 16) {
#pragma unroll
        for (int i = 0; i < 4; ++i) {
            int idx = tid + i * 256;
            int kk = idx & 15;
            int m = idx >> 4;
            int row = block_row + m;
            float v = 0.f;
            if (row < M) v = A[(long)row * K + k0 + kk];
            if (RELU) v = fmaxf(v, 0.f);
            As[kk][m] = v;
        }
#pragma unroll
        for (int i = 0; i < 4; ++i) {
            int idx = tid + i * 256;
            int n = idx & 63;
            int kk = idx >> 6;
            Bs[kk][n] = B[(long)(k0 + kk) * N + block_col + n];
        }
        __syncthreads();
#pragma unroll
        for (int kk = 0; kk < 16; ++kk) {
            float a[4], b[4];
#pragma unroll
            for (int i = 0; i < 4; ++i) a[i] = As[kk][ty * 4 + i];
#pragma unroll
            for (int j = 0; j < 4; ++j) b[j] = Bs[kk][tx * 4 + j];
#pragma unroll
            for (int i = 0; i < 4; ++i)
#pragma unroll
                for (int j = 0; j < 4; ++j) c[i][j] += a[i] * b[j];
        }
        __syncthreads();
    }
#pragma unroll
    for (int i = 0; i < 4; ++i) {
        int row = block_row + ty * 4 + i;
        if (row < M) {
            float* cp = C + (long)row * N + block_col + tx * 4;
#pragma unroll
            for (int j = 0; j < 4; ++j) cp[j] = c[i][j];
        }
    }
}

__global__ __launch_bounds__(256) void scatter_conv(const float* __restrict__ h,
                                                    const int* __restrict__ src,
                                                    const int* __restrict__ dst,
                                                    const float* __restrict__ w,
                                                    float* __restrict__ z, int E) {
    const int lane = threadIdx.x & 63;
    const int wid = threadIdx.x >> 6;
    const int nwaves = (gridDim.x * blockDim.x) >> 6;
    for (int e = blockIdx.x * 4 + wid; e < E; e += nwaves) {
        int s = src[e];
        int d = dst[e];
        float ww = w[e];
        float4 v = ((const float4*)(h + (long)s * NHID))[lane];
        float* zp = z + (long)d * NHID + lane * 4;
        atomicAdd(zp + 0, ww * v.x);
        atomicAdd(zp + 1, ww * v.y);
        atomicAdd(zp + 2, ww * v.z);
        atomicAdd(zp + 3, ww * v.w);
    }
}

__global__ __launch_bounds__(256) void decode_f(const float* __restrict__ z,
                                                const int* __restrict__ ps,
                                                const int* __restrict__ pd,
                                                const float* __restrict__ Wlin,
                                                float* __restrict__ out, int P) {
    const int lane = threadIdx.x & 63;
    const int wid = threadIdx.x >> 6;
    const int nwaves = (gridDim.x * blockDim.x) >> 6;
    float wa[8], wb[8];
#pragma unroll
    for (int i = 0; i < 8; ++i) {
        wa[i] = Wlin[(lane * 4) * 2 + i];
        wb[i] = Wlin[(NHID + lane * 4) * 2 + i];
    }
    for (int p = blockIdx.x * 4 + wid; p < P; p += nwaves) {
        int a = ps[p];
        int b = pd[p];
        float4 va = ((const float4*)(z + (long)a * NHID))[lane];
        float4 vb = ((const float4*)(z + (long)b * NHID))[lane];
        float acc0 = va.x * wa[0] + va.y * wa[2] + va.z * wa[4] + va.w * wa[6]
                   + vb.x * wb[0] + vb.y * wb[2] + vb.z * wb[4] + vb.w * wb[6];
        float acc1 = va.x * wa[1] + va.y * wa[3] + va.z * wa[5] + va.w * wa[7]
                   + vb.x * wb[1] + vb.y * wb[3] + vb.z * wb[5] + vb.w * wb[7];
#pragma unroll
        for (int off = 32; off > 0; off >>= 1) {
            acc0 += __shfl_down(acc0, off);
            acc1 += __shfl_down(acc1, off);
        }
        if (lane == 0) {
            out[(long)p * 2 + 0] = acc0;
            out[(long)p * 2 + 1] = acc1;
        }
    }
}

extern "C" void kernel_launch(void* const* d_in, const int* in_sizes, int n_in,
                              void* d_out, int out_size, void* d_ws, size_t ws_size,
                              hipStream_t stream) {
    (void)n_in; (void)out_size;
    const float* x    = (const float*)d_in[0];   // [M, 512]
    const int*   ei   = (const int*)d_in[1];     // [2, E]
    const float* ew   = (const float*)d_in[2];   // [E]
    const int*   pei  = (const int*)d_in[3];     // [2, P]
    const float* W1   = (const float*)d_in[4];   // [512, 256]
    const float* W2   = (const float*)d_in[5];   // [256, 256]
    const float* Wlin = (const float*)d_in[6];   // [512, 2]
    float* out = (float*)d_out;                  // [P, 2]

    const int E = in_sizes[2];
    const int P = in_sizes[3] / 2;
    const int M = in_sizes[0] / NFEAT;

    dim3 blk(256);
    const int* src = ei;
    const int* dst = ei + E;

    // workspace layout (bf16 path)
    unsigned short* hA = (unsigned short*)d_ws;               // [M,256] bf16
    unsigned short* hB = hA + (size_t)M * NHID;               // [M,256] bf16
    int* offsets = (int*)(hB + (size_t)M * NHID);             // [M+1]
    int* cursor  = offsets + (M + 1);                          // [M]
    unsigned* pk = (unsigned*)(cursor + M);                    // [E] packed (f16 w | u16 src)
    int* blocksums = (int*)(pk + E);                           // [1024]
    float2* za = (float2*)(blocksums + 1024);                  // [M]
    float2* zb = za + M;                                       // [M]
    const size_t need = 2 * (size_t)M * NHID * 2 + ((size_t)2 * M + 1) * 4
                      + (size_t)E * 4 + 1024 * 4 + (size_t)M * 2 * 8;

    if (ws_size >= need && M <= 65535) {
        unsigned short* F1 = (unsigned short*)d_out;          // [131072] bf16 frag (256 KB)
        unsigned short* F2 = F1 + (size_t)NHID * NFEAT;       // [65536] bf16 frag (128 KB)

        const int zt = NFEAT * NHID + NHID * NHID + M;
        prep_frags<<<(zt + 255) / 256, blk, 0, stream>>>(W1, W2, F1, F2, cursor, M);

        // ---- CSR build (XCD-range-partitioned hist + sort) ----
        const int span = (M + 7) / 8;
        const int nb = (M + 1023) / 1024;
        hist_part<<<2048, blk, 0, stream>>>(dst, cursor, E, span, M);
        scan_local<<<nb, 1024, 0, stream>>>(cursor, offsets, blocksums, M);
        scan_sums<<<1, 1024, 0, stream>>>(blocksums, nb);
        scan_finalize<<<(M + 255) / 256, blk, 0, stream>>>(offsets, cursor, blocksums, M, E);
        sort_edges_part<<<2048, blk, 0, stream>>>(src, dst, ew, cursor, pk, E, span, M);

        // ---- Layer 1: hA = cvt(x) @ W1 ----
        const int g = (M + 63) / 64;
        gemm1_tile<<<g, blk, 0, stream>>>(x, F1, hA, M);
        gather_conv_pk<<<(M + 3) / 4, blk, 0, stream>>>(hA, offsets, pk, hB, M);
        // ---- Layer 2 + fused Wlin projection ----
        gemm2_tile<<<g, blk, 0, stream>>>(hB, F2, hA, M);
        gather_wlin_pk<<<(M + 3) / 4, blk, 0, stream>>>(hA, offsets, pk, Wlin, za, zb, M);
        // ---- Decode ----
        decode_pairs<<<(P + 255) / 256, blk, 0, stream>>>(za, zb, pei, pei + P, (float2*)out, P);
    } else {
        // fp32 atomic fallback
        float* bufA = (float*)d_ws;
        float* bufB = bufA + (size_t)M * NHID;
        const size_t zbytes = (size_t)M * NHID * sizeof(float);
        dim3 gemm_grid((M + 63) / 64, NHID / 64);
        gemm_tiled<false><<<gemm_grid, blk, 0, stream>>>(x, W1, bufA, M, NHID, NFEAT);
        hipMemsetAsync(bufB, 0, zbytes, stream);
        scatter_conv<<<2048, blk, 0, stream>>>(bufA, src, dst, ew, bufB, E);
        gemm_tiled<true><<<gemm_grid, blk, 0, stream>>>(bufB, W2, bufA, M, NHID, NHID);
        hipMemsetAsync(bufB, 0, zbytes, stream);
        scatter_conv<<<2048, blk, 0, stream>>>(bufA, src, dst, ew, bufB, E);
        decode_f<<<(P + 3) / 4, blk, 0, stream>>>(bufB, pei, pei + P, Wlin, out, P);
    }
}

// Round 12
// 260.788 us; speedup vs baseline: 1.1366x; 1.0050x over previous
//
#include <hip/hip_runtime.h>

#define NHID 256
#define NFEAT 512

using short8  = __attribute__((ext_vector_type(8))) short;
using float8  = __attribute__((ext_vector_type(8))) float;
using f32x4   = __attribute__((ext_vector_type(4))) float;

__device__ __forceinline__ float b2f(unsigned short u) {
    union { float f; unsigned v; } c;
    c.v = ((unsigned)u) << 16;
    return c.f;
}
__device__ __forceinline__ unsigned short f2b(float f) {
    union { float f; unsigned u; } c;
    c.f = f;
    unsigned r = c.u + 0x7fffu + ((c.u >> 16) & 1u);  // RNE
    return (unsigned short)(r >> 16);
}
__device__ __forceinline__ unsigned short f2h(float f) {
    union { _Float16 h; unsigned short u; } c;
    c.h = (_Float16)f;
    return c.u;
}
__device__ __forceinline__ float h2f(unsigned short u) {
    union { _Float16 h; unsigned short u; } c;
    c.u = u;
    return (float)c.h;
}

// async global->LDS, 16 B/lane; lds base wave-uniform, gsrc per-lane.
__device__ __forceinline__ void gload16(const void* gsrc, void* lds) {
    __builtin_amdgcn_global_load_lds((const __attribute__((address_space(1))) unsigned int*)gsrc,
                                     (__attribute__((address_space(3))) unsigned int*)lds,
                                     16, 0, 0);
}

// ---------------- W -> MFMA-fragment layout + cursor zero ----------------
__global__ __launch_bounds__(256) void prep_frags(const float* __restrict__ W1,
                                                  const float* __restrict__ W2,
                                                  unsigned short* __restrict__ F1,
                                                  unsigned short* __restrict__ F2,
                                                  int* __restrict__ cursor, int M) {
    int i = blockIdx.x * blockDim.x + threadIdx.x;
    const int T1 = NFEAT * NHID;
    const int T2 = NHID * NHID;
    if (i < T1) {
        int j = i & 7, l = (i >> 3) & 63, cb = (i >> 9) & 15, t = i >> 13;
        int n = cb * 16 + (l & 15);
        int k = t * 32 + ((l >> 4) << 3) + j;
        F1[i] = f2b(W1[k * NHID + n]);
    } else if (i < T1 + T2) {
        int i2 = i - T1;
        int j = i2 & 7, l = (i2 >> 3) & 63, cb = (i2 >> 9) & 15, t = i2 >> 13;
        int n = cb * 16 + (l & 15);
        int k = t * 32 + ((l >> 4) << 3) + j;
        F2[i2] = f2b(W2[k * NHID + n]);
    } else {
        int j = i - T1 - T2;
        if (j < M) cursor[j] = 0;
    }
}

// ---------------- GEMM1: C[M,256] = cvt_bf16(x[M,512]) @ W1 ----------------
// 64x256 tile, 4 waves. 3-buffer LDS, depth-2 gload pipeline, WAIT-FIRST ordering:
// vmcnt(N) -> s_barrier -> STAGE(t+2) -> ds_read/MFMA.  (race-free: buffer being
// overwritten was last read strictly before this iteration's barrier)
__global__ __launch_bounds__(256) void gemm1_pipe(const float* __restrict__ x,
                                                  const unsigned short* __restrict__ F1,
                                                  unsigned short* __restrict__ C, int M) {
    __shared__ float As[3][64 * 32];            // fp32 tile, XOR-swizzled: 8 KB/buf
    __shared__ unsigned short Bs[3][8192];      // fragment order: 16 KB/buf
    const int tid = threadIdx.x;
    const int lane = tid & 63;
    const int wc = tid >> 6;
    const int brow = blockIdx.x * 64;
    const int lrow = lane & 15;
    const int lq = lane >> 4;
    const int nt = NFEAT / 32;   // 16

    // A gload source (both-sides swizzle: pre-swizzled global chunk)
    int ar0 = brow + wc * 16 + (lane >> 3);
    int ar1 = ar0 + 8;
    if (ar0 >= M) ar0 = M - 1;
    if (ar1 >= M) ar1 = M - 1;
    const int aswz = ((lane & 7) ^ (lane >> 3)) * 4;   // fp32 elems
    const float* ag0 = x + (size_t)ar0 * NFEAT + aswz;
    const float* ag1 = x + (size_t)ar1 * NFEAT + aswz;
    const unsigned short* bsrc = F1 + (wc * 4) * 512 + lane * 8;

    f32x4 acc[4][4] = {};

#define STAGE1(bf, t) do { \
        gload16(ag0 + (t) * 32, (char*)&As[bf][0] + wc * 2048); \
        gload16(ag1 + (t) * 32, (char*)&As[bf][0] + wc * 2048 + 1024); \
        const unsigned short* bs_ = bsrc + (t) * 8192; \
        gload16(bs_ + 0 * 512, &Bs[bf][(wc * 4 + 0) * 512]); \
        gload16(bs_ + 1 * 512, &Bs[bf][(wc * 4 + 1) * 512]); \
        gload16(bs_ + 2 * 512, &Bs[bf][(wc * 4 + 2) * 512]); \
        gload16(bs_ + 3 * 512, &Bs[bf][(wc * 4 + 3) * 512]); \
    } while (0)

    STAGE1(0, 0);
    STAGE1(1, 1);

#pragma unroll
    for (int t = 0; t < 16; ++t) {
        if (t < nt - 1) asm volatile("s_waitcnt vmcnt(6)" ::: "memory");
        else            asm volatile("s_waitcnt vmcnt(0)" ::: "memory");
        __builtin_amdgcn_s_barrier();
        __builtin_amdgcn_sched_barrier(0);
        if (t + 2 < nt) STAGE1((t + 2) % 3, t + 2);

        const int rb = t % 3;
        short8 a[4], b[4];
#pragma unroll
        for (int m = 0; m < 4; ++m) {
            int row = m * 16 + lrow;
            const char* base = (const char*)&As[rb][0] + row * 128;
            int sw = (row & 7) << 4;
            float4 f0 = *(const float4*)(base + ((lq * 32) ^ sw));
            float4 f1 = *(const float4*)(base + ((lq * 32 + 16) ^ sw));
            short8 v;
            v[0] = (short)f2b(f0.x); v[1] = (short)f2b(f0.y);
            v[2] = (short)f2b(f0.z); v[3] = (short)f2b(f0.w);
            v[4] = (short)f2b(f1.x); v[5] = (short)f2b(f1.y);
            v[6] = (short)f2b(f1.z); v[7] = (short)f2b(f1.w);
            a[m] = v;
        }
#pragma unroll
        for (int n = 0; n < 4; ++n)
            b[n] = *(const short8*)(&Bs[rb][(wc * 4 + n) * 512 + lane * 8]);
#pragma unroll
        for (int m = 0; m < 4; ++m)
#pragma unroll
            for (int n = 0; n < 4; ++n)
                acc[m][n] = __builtin_amdgcn_mfma_f32_16x16x32_bf16(a[m], b[n], acc[m][n], 0, 0, 0);
    }
#undef STAGE1

#pragma unroll
    for (int m = 0; m < 4; ++m)
#pragma unroll
        for (int r = 0; r < 4; ++r) {
            int row = brow + m * 16 + (lane >> 4) * 4 + r;
            if (row < M) {
#pragma unroll
                for (int n = 0; n < 4; ++n) {
                    int col = wc * 64 + n * 16 + (lane & 15);
                    C[(size_t)row * NHID + col] = f2b(acc[m][n][r]);
                }
            }
        }
}

// ---------------- GEMM2: C[M,256] = A_bf16[M,256] @ W2 (same wait-first pipeline) ----------------
__global__ __launch_bounds__(256) void gemm2_pipe(const unsigned short* __restrict__ A,
                                                  const unsigned short* __restrict__ F2,
                                                  unsigned short* __restrict__ C, int M) {
    __shared__ unsigned short As[3][2048];      // bf16 tile, swizzled: 4 KB/buf
    __shared__ unsigned short Bs[3][8192];      // 16 KB/buf
    const int tid = threadIdx.x;
    const int lane = tid & 63;
    const int wc = tid >> 6;
    const int brow = blockIdx.x * 64;
    const int lrow = lane & 15;
    const int lq = lane >> 4;
    const int nt = NHID / 32;   // 8

    int ar = brow + wc * 16 + (lane >> 2);
    if (ar >= M) ar = M - 1;
    const int aswz = ((lane & 3) ^ ((lane >> 2) & 3)) * 8;   // shorts
    const unsigned short* agp = A + (size_t)ar * NHID + aswz;
    const unsigned short* bsrc = F2 + (wc * 4) * 512 + lane * 8;

    f32x4 acc[4][4] = {};

#define STAGE2(bf, t) do { \
        gload16(agp + (t) * 32, (char*)&As[bf][0] + wc * 1024); \
        const unsigned short* bs_ = bsrc + (t) * 8192; \
        gload16(bs_ + 0 * 512, &Bs[bf][(wc * 4 + 0) * 512]); \
        gload16(bs_ + 1 * 512, &Bs[bf][(wc * 4 + 1) * 512]); \
        gload16(bs_ + 2 * 512, &Bs[bf][(wc * 4 + 2) * 512]); \
        gload16(bs_ + 3 * 512, &Bs[bf][(wc * 4 + 3) * 512]); \
    } while (0)

    STAGE2(0, 0);
    STAGE2(1, 1);

#pragma unroll
    for (int t = 0; t < 8; ++t) {
        if (t < nt - 1) asm volatile("s_waitcnt vmcnt(5)" ::: "memory");
        else            asm volatile("s_waitcnt vmcnt(0)" ::: "memory");
        __builtin_amdgcn_s_barrier();
        __builtin_amdgcn_sched_barrier(0);
        if (t + 2 < nt) STAGE2((t + 2) % 3, t + 2);

        const int rb = t % 3;
        short8 a[4], b[4];
#pragma unroll
        for (int m = 0; m < 4; ++m) {
            int row = m * 16 + lrow;
            a[m] = *(const short8*)((const char*)&As[rb][0] + row * 64 + ((lq * 16) ^ ((row & 3) << 4)));
        }
#pragma unroll
        for (int n = 0; n < 4; ++n)
            b[n] = *(const short8*)(&Bs[rb][(wc * 4 + n) * 512 + lane * 8]);
#pragma unroll
        for (int m = 0; m < 4; ++m)
#pragma unroll
            for (int n = 0; n < 4; ++n)
                acc[m][n] = __builtin_amdgcn_mfma_f32_16x16x32_bf16(a[m], b[n], acc[m][n], 0, 0, 0);
    }
#undef STAGE2

#pragma unroll
    for (int m = 0; m < 4; ++m)
#pragma unroll
        for (int r = 0; r < 4; ++r) {
            int row = brow + m * 16 + (lane >> 4) * 4 + r;
            if (row < M) {
#pragma unroll
                for (int n = 0; n < 4; ++n) {
                    int col = wc * 64 + n * 16 + (lane & 15);
                    C[(size_t)row * NHID + col] = f2b(acc[m][n][r]);
                }
            }
        }
}

// ---------------- CSR build, XCD-range-partitioned ----------------
__global__ __launch_bounds__(256) void hist_part(const int* __restrict__ dst,
                                                 int* __restrict__ counts,
                                                 int E, int span, int M) {
    const int g = blockIdx.x & 7;
    const int rank = blockIdx.x >> 3;
    const int nrank = gridDim.x >> 3;
    const int lo = g * span;
    const int hi = min(lo + span, M);
    for (int e = rank * blockDim.x + threadIdx.x; e < E; e += nrank * blockDim.x) {
        int d = dst[e];
        if (d >= lo && d < hi) atomicAdd(&counts[d], 1);
    }
}

__global__ __launch_bounds__(1024) void scan_local(const int* __restrict__ counts,
                                                   int* __restrict__ local,
                                                   int* __restrict__ blocksums, int n) {
    __shared__ int s[1024];
    const int tid = threadIdx.x;
    const int idx = blockIdx.x * 1024 + tid;
    int v = (idx < n) ? counts[idx] : 0;
    s[tid] = v;
    __syncthreads();
    for (int off = 1; off < 1024; off <<= 1) {
        int t = (tid >= off) ? s[tid - off] : 0;
        __syncthreads();
        s[tid] += t;
        __syncthreads();
    }
    if (idx < n) local[idx] = s[tid] - v;
    if (tid == 1023) blocksums[blockIdx.x] = s[1023];
}

__global__ __launch_bounds__(1024) void scan_sums(int* __restrict__ blocksums, int nb) {
    __shared__ int s[1024];
    const int tid = threadIdx.x;
    int v = (tid < nb) ? blocksums[tid] : 0;
    s[tid] = v;
    __syncthreads();
    for (int off = 1; off < 1024; off <<= 1) {
        int t = (tid >= off) ? s[tid - off] : 0;
        __syncthreads();
        s[tid] += t;
        __syncthreads();
    }
    if (tid < nb) blocksums[tid] = s[tid] - v;
}

__global__ __launch_bounds__(256) void scan_finalize(int* __restrict__ offsets,
                                                     int* __restrict__ cursor,
                                                     const int* __restrict__ blockoffs,
                                                     int n, int total) {
    int idx = blockIdx.x * blockDim.x + threadIdx.x;
    if (idx < n) {
        int o = offsets[idx] + blockoffs[idx >> 10];
        offsets[idx] = o;
        cursor[idx] = o;
    }
    if (idx == 0) offsets[n] = total;
}

__global__ __launch_bounds__(256) void sort_edges_part(const int* __restrict__ src,
                                                       const int* __restrict__ dst,
                                                       const float* __restrict__ w,
                                                       int* __restrict__ cursor,
                                                       unsigned* __restrict__ pk,
                                                       int E, int span, int M) {
    const int g = blockIdx.x & 7;
    const int rank = blockIdx.x >> 3;
    const int nrank = gridDim.x >> 3;
    const int lo = g * span;
    const int hi = min(lo + span, M);
    for (int e = rank * blockDim.x + threadIdx.x; e < E; e += nrank * blockDim.x) {
        int d = dst[e];
        if (d >= lo && d < hi) {
            int pos = atomicAdd(&cursor[d], 1);
            pk[pos] = ((unsigned)f2h(w[e]) << 16) | (unsigned)src[e];
        }
    }
}

// ---------------- Gather conv layer-1 (bf16 h -> relu -> bf16 z) ----------------
__global__ __launch_bounds__(256) void gather_conv_pk(const unsigned short* __restrict__ h,
                                                      const int* __restrict__ offsets,
                                                      const unsigned* __restrict__ pk,
                                                      unsigned short* __restrict__ z, int N) {
    const int lane = threadIdx.x & 63;
    const int wid = threadIdx.x >> 6;
    const int node = blockIdx.x * 4 + wid;
    if (node >= N) return;
    const int s0 = offsets[node];
    const int s1 = offsets[node + 1];
    float a0 = 0.f, a1 = 0.f, a2 = 0.f, a3 = 0.f;
    int i = s0;
    for (; i + 4 <= s1; i += 4) {
        unsigned qA = pk[i], qB = pk[i + 1], qC = pk[i + 2], qD = pk[i + 3];
        float wA = h2f(qA >> 16), wB = h2f(qB >> 16), wC = h2f(qC >> 16), wD = h2f(qD >> 16);
        ushort4 vA = ((const ushort4*)(h + (size_t)(qA & 0xffffu) * NHID))[lane];
        ushort4 vB = ((const ushort4*)(h + (size_t)(qB & 0xffffu) * NHID))[lane];
        ushort4 vC = ((const ushort4*)(h + (size_t)(qC & 0xffffu) * NHID))[lane];
        ushort4 vD = ((const ushort4*)(h + (size_t)(qD & 0xffffu) * NHID))[lane];
        a0 += wA * b2f(vA.x) + wB * b2f(vB.x) + wC * b2f(vC.x) + wD * b2f(vD.x);
        a1 += wA * b2f(vA.y) + wB * b2f(vB.y) + wC * b2f(vC.y) + wD * b2f(vD.y);
        a2 += wA * b2f(vA.z) + wB * b2f(vB.z) + wC * b2f(vC.z) + wD * b2f(vD.z);
        a3 += wA * b2f(vA.w) + wB * b2f(vB.w) + wC * b2f(vC.w) + wD * b2f(vD.w);
    }
    for (; i < s1; ++i) {
        unsigned q = pk[i];
        float ww = h2f(q >> 16);
        ushort4 v = ((const ushort4*)(h + (size_t)(q & 0xffffu) * NHID))[lane];
        a0 += ww * b2f(v.x);
        a1 += ww * b2f(v.y);
        a2 += ww * b2f(v.z);
        a3 += ww * b2f(v.w);
    }
    a0 = fmaxf(a0, 0.f); a1 = fmaxf(a1, 0.f);
    a2 = fmaxf(a2, 0.f); a3 = fmaxf(a3, 0.f);
    ushort4 o;
    o.x = f2b(a0); o.y = f2b(a1); o.z = f2b(a2); o.w = f2b(a3);
    ((ushort4*)(z + (size_t)node * NHID))[lane] = o;
}

// ---------------- Gather conv layer-2 fused with Wlin projection ----------------
__global__ __launch_bounds__(256) void gather_wlin_pk(const unsigned short* __restrict__ h,
                                                      const int* __restrict__ offsets,
                                                      const unsigned* __restrict__ pk,
                                                      const float* __restrict__ Wlin,
                                                      float2* __restrict__ za,
                                                      float2* __restrict__ zb, int N) {
    const int lane = threadIdx.x & 63;
    const int wid = threadIdx.x >> 6;
    const int node = blockIdx.x * 4 + wid;
    if (node >= N) return;

    float wt[8], wbm[8];
#pragma unroll
    for (int i = 0; i < 8; ++i) {
        wt[i]  = Wlin[(lane * 4) * 2 + i];
        wbm[i] = Wlin[(NHID + lane * 4) * 2 + i];
    }

    const int s0 = offsets[node];
    const int s1 = offsets[node + 1];
    float a0 = 0.f, a1 = 0.f, a2 = 0.f, a3 = 0.f;
    int i = s0;
    for (; i + 4 <= s1; i += 4) {
        unsigned qA = pk[i], qB = pk[i + 1], qC = pk[i + 2], qD = pk[i + 3];
        float wA = h2f(qA >> 16), wB = h2f(qB >> 16), wC = h2f(qC >> 16), wD = h2f(qD >> 16);
        ushort4 vA = ((const ushort4*)(h + (size_t)(qA & 0xffffu) * NHID))[lane];
        ushort4 vB = ((const ushort4*)(h + (size_t)(qB & 0xffffu) * NHID))[lane];
        ushort4 vC = ((const ushort4*)(h + (size_t)(qC & 0xffffu) * NHID))[lane];
        ushort4 vD = ((const ushort4*)(h + (size_t)(qD & 0xffffu) * NHID))[lane];
        a0 += wA * b2f(vA.x) + wB * b2f(vB.x) + wC * b2f(vC.x) + wD * b2f(vD.x);
        a1 += wA * b2f(vA.y) + wB * b2f(vB.y) + wC * b2f(vC.y) + wD * b2f(vD.y);
        a2 += wA * b2f(vA.z) + wB * b2f(vB.z) + wC * b2f(vC.z) + wD * b2f(vD.z);
        a3 += wA * b2f(vA.w) + wB * b2f(vB.w) + wC * b2f(vC.w) + wD * b2f(vD.w);
    }
    for (; i < s1; ++i) {
        unsigned q = pk[i];
        float ww = h2f(q >> 16);
        ushort4 v = ((const ushort4*)(h + (size_t)(q & 0xffffu) * NHID))[lane];
        a0 += ww * b2f(v.x);
        a1 += ww * b2f(v.y);
        a2 += ww * b2f(v.z);
        a3 += ww * b2f(v.w);
    }

    float pa0 = a0 * wt[0] + a1 * wt[2] + a2 * wt[4] + a3 * wt[6];
    float pa1 = a0 * wt[1] + a1 * wt[3] + a2 * wt[5] + a3 * wt[7];
    float pb0 = a0 * wbm[0] + a1 * wbm[2] + a2 * wbm[4] + a3 * wbm[6];
    float pb1 = a0 * wbm[1] + a1 * wbm[3] + a2 * wbm[5] + a3 * wbm[7];
#pragma unroll
    for (int off = 32; off > 0; off >>= 1) {
        pa0 += __shfl_down(pa0, off);
        pa1 += __shfl_down(pa1, off);
        pb0 += __shfl_down(pb0, off);
        pb1 += __shfl_down(pb1, off);
    }
    if (lane == 0) {
        za[node] = {pa0, pa1};
        zb[node] = {pb0, pb1};
    }
}

// ---------------- Decode: out[p] = za[ps[p]] + zb[pd[p]] ----------------
__global__ __launch_bounds__(256) void decode_pairs(const float2* __restrict__ za,
                                                    const float2* __restrict__ zb,
                                                    const int* __restrict__ ps,
                                                    const int* __restrict__ pd,
                                                    float2* __restrict__ out, int P) {
    int p = blockIdx.x * blockDim.x + threadIdx.x;
    if (p < P) {
        float2 va = za[ps[p]];
        float2 vb = zb[pd[p]];
        out[p] = {va.x + vb.x, va.y + vb.y};
    }
}

// ================= fp32 fallback path (ws too small or M > 65535) =================
template <bool RELU>
__global__ __launch_bounds__(256) void gemm_tiled(const float* __restrict__ A,
                                                  const float* __restrict__ B,
                                                  float* __restrict__ C,
                                                  int M, int N, int K) {
    __shared__ float As[16][65];
    __shared__ float Bs[16][64];
    const int block_row = blockIdx.x * 64;
    const int block_col = blockIdx.y * 64;
    const int tid = threadIdx.x;
    const int tx = tid & 15;
    const int ty = tid >> 4;
    float c[4][4] = {};
    for (int k0 = 0; k0 < K; k0 += 16) {
#pragma unroll
        for (int i = 0; i < 4; ++i) {
            int idx = tid + i * 256;
            int kk = idx & 15;
            int m = idx >> 4;
            int row = block_row + m;
            float v = 0.f;
            if (row < M) v = A[(long)row * K + k0 + kk];
            if (RELU) v = fmaxf(v, 0.f);
            As[kk][m] = v;
        }
#pragma unroll
        for (int i = 0; i < 4; ++i) {
            int idx = tid + i * 256;
            int n = idx & 63;
            int kk = idx >> 6;
            Bs[kk][n] = B[(long)(k0 + kk) * N + block_col + n];
        }
        __syncthreads();
#pragma unroll
        for (int kk = 0; kk < 16; ++kk) {
            float a[4], b[4];
#pragma unroll
            for (int i = 0; i < 4; ++i) a[i] = As[kk][ty * 4 + i];
#pragma unroll
            for (int j = 0; j < 4; ++j) b[j] = Bs[kk][tx * 4 + j];
#pragma unroll
            for (int i = 0; i < 4; ++i)
#pragma unroll
                for (int j = 0; j < 4; ++j) c[i][j] += a[i] * b[j];
        }
        __syncthreads();
    }
#pragma unroll
    for (int i = 0; i < 4; ++i) {
        int row = block_row + ty * 4 + i;
        if (row < M) {
            float* cp = C + (long)row * N + block_col + tx * 4;
#pragma unroll
            for (int j = 0; j < 4; ++j) cp[j] = c[i][j];
        }
    }
}

__global__ __launch_bounds__(256) void scatter_conv(const float* __restrict__ h,
                                                    const int* __restrict__ src,
                                                    const int* __restrict__ dst,
                                                    const float* __restrict__ w,
                                                    float* __restrict__ z, int E) {
    const int lane = threadIdx.x & 63;
    const int wid = threadIdx.x >> 6;
    const int nwaves = (gridDim.x * blockDim.x) >> 6;
    for (int e = blockIdx.x * 4 + wid; e < E; e += nwaves) {
        int s = src[e];
        int d = dst[e];
        float ww = w[e];
        float4 v = ((const float4*)(h + (long)s * NHID))[lane];
        float* zp = z + (long)d * NHID + lane * 4;
        atomicAdd(zp + 0, ww * v.x);
        atomicAdd(zp + 1, ww * v.y);
        atomicAdd(zp + 2, ww * v.z);
        atomicAdd(zp + 3, ww * v.w);
    }
}

__global__ __launch_bounds__(256) void decode_f(const float* __restrict__ z,
                                                const int* __restrict__ ps,
                                                const int* __restrict__ pd,
                                                const float* __restrict__ Wlin,
                                                float* __restrict__ out, int P) {
    const int lane = threadIdx.x & 63;
    const int wid = threadIdx.x >> 6;
    const int nwaves = (gridDim.x * blockDim.x) >> 6;
    float wa[8], wb[8];
#pragma unroll
    for (int i = 0; i < 8; ++i) {
        wa[i] = Wlin[(lane * 4) * 2 + i];
        wb[i] = Wlin[(NHID + lane * 4) * 2 + i];
    }
    for (int p = blockIdx.x * 4 + wid; p < P; p += nwaves) {
        int a = ps[p];
        int b = pd[p];
        float4 va = ((const float4*)(z + (long)a * NHID))[lane];
        float4 vb = ((const float4*)(z + (long)b * NHID))[lane];
        float acc0 = va.x * wa[0] + va.y * wa[2] + va.z * wa[4] + va.w * wa[6]
                   + vb.x * wb[0] + vb.y * wb[2] + vb.z * wb[4] + vb.w * wb[6];
        float acc1 = va.x * wa[1] + va.y * wa[3] + va.z * wa[5] + va.w * wa[7]
                   + vb.x * wb[1] + vb.y * wb[3] + vb.z * wb[5] + vb.w * wb[7];
#pragma unroll
        for (int off = 32; off > 0; off >>= 1) {
            acc0 += __shfl_down(acc0, off);
            acc1 += __shfl_down(acc1, off);
        }
        if (lane == 0) {
            out[(long)p * 2 + 0] = acc0;
            out[(long)p * 2 + 1] = acc1;
        }
    }
}

extern "C" void kernel_launch(void* const* d_in, const int* in_sizes, int n_in,
                              void* d_out, int out_size, void* d_ws, size_t ws_size,
                              hipStream_t stream) {
    (void)n_in; (void)out_size;
    const float* x    = (const float*)d_in[0];   // [M, 512]
    const int*   ei   = (const int*)d_in[1];     // [2, E]
    const float* ew   = (const float*)d_in[2];   // [E]
    const int*   pei  = (const int*)d_in[3];     // [2, P]
    const float* W1   = (const float*)d_in[4];   // [512, 256]
    const float* W2   = (const float*)d_in[5];   // [256, 256]
    const float* Wlin = (const float*)d_in[6];   // [512, 2]
    float* out = (float*)d_out;                  // [P, 2]

    const int E = in_sizes[2];
    const int P = in_sizes[3] / 2;
    const int M = in_sizes[0] / NFEAT;

    dim3 blk(256);
    const int* src = ei;
    const int* dst = ei + E;

    // workspace layout (bf16 path)
    unsigned short* hA = (unsigned short*)d_ws;               // [M,256] bf16
    unsigned short* hB = hA + (size_t)M * NHID;               // [M,256] bf16
    int* offsets = (int*)(hB + (size_t)M * NHID);             // [M+1]
    int* cursor  = offsets + (M + 1);                          // [M]
    unsigned* pk = (unsigned*)(cursor + M);                    // [E]
    int* blocksums = (int*)(pk + E);                           // [1024]
    float2* za = (float2*)(blocksums + 1024);                  // [M]
    float2* zb = za + M;                                       // [M]
    const size_t need = 2 * (size_t)M * NHID * 2 + ((size_t)2 * M + 1) * 4
                      + (size_t)E * 4 + 1024 * 4 + (size_t)M * 2 * 8;

    if (ws_size >= need && M <= 65535) {
        unsigned short* F1 = (unsigned short*)d_out;          // 256 KB frag buffer
        unsigned short* F2 = F1 + (size_t)NHID * NFEAT;       // 128 KB

        const int zt = NFEAT * NHID + NHID * NHID + M;
        prep_frags<<<(zt + 255) / 256, blk, 0, stream>>>(W1, W2, F1, F2, cursor, M);

        // ---- CSR build (XCD-range-partitioned hist + sort) ----
        const int span = (M + 7) / 8;
        const int nb = (M + 1023) / 1024;
        hist_part<<<2048, blk, 0, stream>>>(dst, cursor, E, span, M);
        scan_local<<<nb, 1024, 0, stream>>>(cursor, offsets, blocksums, M);
        scan_sums<<<1, 1024, 0, stream>>>(blocksums, nb);
        scan_finalize<<<(M + 255) / 256, blk, 0, stream>>>(offsets, cursor, blocksums, M, E);
        sort_edges_part<<<2048, blk, 0, stream>>>(src, dst, ew, cursor, pk, E, span, M);

        // ---- Layer 1 ----
        const int g = (M + 63) / 64;
        gemm1_pipe<<<g, blk, 0, stream>>>(x, F1, hA, M);
        gather_conv_pk<<<(M + 3) / 4, blk, 0, stream>>>(hA, offsets, pk, hB, M);
        // ---- Layer 2 + fused Wlin projection ----
        gemm2_pipe<<<g, blk, 0, stream>>>(hB, F2, hA, M);
        gather_wlin_pk<<<(M + 3) / 4, blk, 0, stream>>>(hA, offsets, pk, Wlin, za, zb, M);
        // ---- Decode ----
        decode_pairs<<<(P + 255) / 256, blk, 0, stream>>>(za, zb, pei, pei + P, (float2*)out, P);
    } else {
        // fp32 atomic fallback
        float* bufA = (float*)d_ws;
        float* bufB = bufA + (size_t)M * NHID;
        const size_t zbytes = (size_t)M * NHID * sizeof(float);
        dim3 gemm_grid((M + 63) / 64, NHID / 64);
        gemm_tiled<false><<<gemm_grid, blk, 0, stream>>>(x, W1, bufA, M, NHID, NFEAT);
        hipMemsetAsync(bufB, 0, zbytes, stream);
        scatter_conv<<<2048, blk, 0, stream>>>(bufA, src, dst, ew, bufB, E);
        gemm_tiled<true><<<gemm_grid, blk, 0, stream>>>(bufB, W2, bufA, M, NHID, NHID);
        hipMemsetAsync(bufB, 0, zbytes, stream);
        scatter_conv<<<2048, blk, 0, stream>>>(bufA, src, dst, ew, bufB, E);
        decode_f<<<(P + 3) / 4, blk, 0, stream>>>(bufB, pei, pei + P, Wlin, out, P);
    }
}

// Round 13
// 204.122 us; speedup vs baseline: 1.4521x; 1.2776x over previous
//
#include <hip/hip_runtime.h>

#define NHID 256
#define NFEAT 512

using short8  = __attribute__((ext_vector_type(8))) short;
using float8  = __attribute__((ext_vector_type(8))) float;
using f32x4   = __attribute__((ext_vector_type(4))) float;

__device__ __forceinline__ float b2f(unsigned short u) {
    union { float f; unsigned v; } c;
    c.v = ((unsigned)u) << 16;
    return c.f;
}
__device__ __forceinline__ unsigned short f2b(float f) {
    union { float f; unsigned u; } c;
    c.f = f;
    unsigned r = c.u + 0x7fffu + ((c.u >> 16) & 1u);  // RNE
    return (unsigned short)(r >> 16);
}
__device__ __forceinline__ unsigned short f2h(float f) {
    union { _Float16 h; unsigned short u; } c;
    c.h = (_Float16)f;
    return c.u;
}
__device__ __forceinline__ float h2f(unsigned short u) {
    union { _Float16 h; unsigned short u; } c;
    c.u = u;
    return (float)c.h;
}

// async global->LDS, 16 B/lane; lds base wave-uniform, gsrc per-lane.
__device__ __forceinline__ void gload16(const void* gsrc, void* lds) {
    __builtin_amdgcn_global_load_lds((const __attribute__((address_space(1))) unsigned int*)gsrc,
                                     (__attribute__((address_space(3))) unsigned int*)lds,
                                     16, 0, 0);
}

// ---------------- prep: W1 -> MFMA frags, WP = W2 @ [Wlin_top|Wlin_bot], cursor zero ----------------
__global__ __launch_bounds__(256) void prep_all(const float* __restrict__ W1,
                                                const float* __restrict__ W2,
                                                const float* __restrict__ Wlin,
                                                unsigned short* __restrict__ F1,
                                                float* __restrict__ WP,
                                                int* __restrict__ cursor, int M) {
    int i = blockIdx.x * blockDim.x + threadIdx.x;
    const int T1 = NFEAT * NHID;   // 131072
    if (i < T1) {
        int j = i & 7, l = (i >> 3) & 63, cb = (i >> 9) & 15, t = i >> 13;
        int n = cb * 16 + (l & 15);
        int k = t * 32 + ((l >> 4) << 3) + j;
        F1[i] = f2b(W1[k * NHID + n]);
    } else if (i < T1 + NHID * 4) {
        int i3 = i - T1;
        int k = i3 >> 2, j = i3 & 3;
        const int base = (j >= 2) ? NHID : 0;   // top half rows vs bottom half rows of Wlin
        const int col = j & 1;
        float acc = 0.f;
        for (int n = 0; n < NHID; ++n)
            acc += W2[k * NHID + n] * Wlin[(base + n) * 2 + col];
        WP[k * 4 + j] = acc;
    } else {
        int j = i - T1 - NHID * 4;
        if (j < M) cursor[j] = 0;
    }
}

// ---------------- GEMM1: C[M,256] = cvt_bf16(x[M,512]) @ W1 ----------------
// (round-12 verified kernel, unchanged) 64x256 tile, 4 waves, 3-buffer LDS,
// depth-2 gload pipeline, wait-first counted vmcnt.
__global__ __launch_bounds__(256) void gemm1_pipe(const float* __restrict__ x,
                                                  const unsigned short* __restrict__ F1,
                                                  unsigned short* __restrict__ C, int M) {
    __shared__ float As[3][64 * 32];
    __shared__ unsigned short Bs[3][8192];
    const int tid = threadIdx.x;
    const int lane = tid & 63;
    const int wc = tid >> 6;
    const int brow = blockIdx.x * 64;
    const int lrow = lane & 15;
    const int lq = lane >> 4;
    const int nt = NFEAT / 32;   // 16

    int ar0 = brow + wc * 16 + (lane >> 3);
    int ar1 = ar0 + 8;
    if (ar0 >= M) ar0 = M - 1;
    if (ar1 >= M) ar1 = M - 1;
    const int aswz = ((lane & 7) ^ (lane >> 3)) * 4;
    const float* ag0 = x + (size_t)ar0 * NFEAT + aswz;
    const float* ag1 = x + (size_t)ar1 * NFEAT + aswz;
    const unsigned short* bsrc = F1 + (wc * 4) * 512 + lane * 8;

    f32x4 acc[4][4] = {};

#define STAGE1(bf, t) do { \
        gload16(ag0 + (t) * 32, (char*)&As[bf][0] + wc * 2048); \
        gload16(ag1 + (t) * 32, (char*)&As[bf][0] + wc * 2048 + 1024); \
        const unsigned short* bs_ = bsrc + (t) * 8192; \
        gload16(bs_ + 0 * 512, &Bs[bf][(wc * 4 + 0) * 512]); \
        gload16(bs_ + 1 * 512, &Bs[bf][(wc * 4 + 1) * 512]); \
        gload16(bs_ + 2 * 512, &Bs[bf][(wc * 4 + 2) * 512]); \
        gload16(bs_ + 3 * 512, &Bs[bf][(wc * 4 + 3) * 512]); \
    } while (0)

    STAGE1(0, 0);
    STAGE1(1, 1);

#pragma unroll
    for (int t = 0; t < 16; ++t) {
        if (t < nt - 1) asm volatile("s_waitcnt vmcnt(6)" ::: "memory");
        else            asm volatile("s_waitcnt vmcnt(0)" ::: "memory");
        __builtin_amdgcn_s_barrier();
        __builtin_amdgcn_sched_barrier(0);
        if (t + 2 < nt) STAGE1((t + 2) % 3, t + 2);

        const int rb = t % 3;
        short8 a[4], b[4];
#pragma unroll
        for (int m = 0; m < 4; ++m) {
            int row = m * 16 + lrow;
            const char* base = (const char*)&As[rb][0] + row * 128;
            int sw = (row & 7) << 4;
            float4 f0 = *(const float4*)(base + ((lq * 32) ^ sw));
            float4 f1 = *(const float4*)(base + ((lq * 32 + 16) ^ sw));
            short8 v;
            v[0] = (short)f2b(f0.x); v[1] = (short)f2b(f0.y);
            v[2] = (short)f2b(f0.z); v[3] = (short)f2b(f0.w);
            v[4] = (short)f2b(f1.x); v[5] = (short)f2b(f1.y);
            v[6] = (short)f2b(f1.z); v[7] = (short)f2b(f1.w);
            a[m] = v;
        }
#pragma unroll
        for (int n = 0; n < 4; ++n)
            b[n] = *(const short8*)(&Bs[rb][(wc * 4 + n) * 512 + lane * 8]);
#pragma unroll
        for (int m = 0; m < 4; ++m)
#pragma unroll
            for (int n = 0; n < 4; ++n)
                acc[m][n] = __builtin_amdgcn_mfma_f32_16x16x32_bf16(a[m], b[n], acc[m][n], 0, 0, 0);
    }
#undef STAGE1

#pragma unroll
    for (int m = 0; m < 4; ++m)
#pragma unroll
        for (int r = 0; r < 4; ++r) {
            int row = brow + m * 16 + (lane >> 4) * 4 + r;
            if (row < M) {
#pragma unroll
                for (int n = 0; n < 4; ++n) {
                    int col = wc * 64 + n * 16 + (lane & 15);
                    C[(size_t)row * NHID + col] = f2b(acc[m][n][r]);
                }
            }
        }
}

// ---------------- CSR build, XCD-range-partitioned (unchanged) ----------------
__global__ __launch_bounds__(256) void hist_part(const int* __restrict__ dst,
                                                 int* __restrict__ counts,
                                                 int E, int span, int M) {
    const int g = blockIdx.x & 7;
    const int rank = blockIdx.x >> 3;
    const int nrank = gridDim.x >> 3;
    const int lo = g * span;
    const int hi = min(lo + span, M);
    for (int e = rank * blockDim.x + threadIdx.x; e < E; e += nrank * blockDim.x) {
        int d = dst[e];
        if (d >= lo && d < hi) atomicAdd(&counts[d], 1);
    }
}

__global__ __launch_bounds__(1024) void scan_local(const int* __restrict__ counts,
                                                   int* __restrict__ local,
                                                   int* __restrict__ blocksums, int n) {
    __shared__ int s[1024];
    const int tid = threadIdx.x;
    const int idx = blockIdx.x * 1024 + tid;
    int v = (idx < n) ? counts[idx] : 0;
    s[tid] = v;
    __syncthreads();
    for (int off = 1; off < 1024; off <<= 1) {
        int t = (tid >= off) ? s[tid - off] : 0;
        __syncthreads();
        s[tid] += t;
        __syncthreads();
    }
    if (idx < n) local[idx] = s[tid] - v;
    if (tid == 1023) blocksums[blockIdx.x] = s[1023];
}

__global__ __launch_bounds__(1024) void scan_sums(int* __restrict__ blocksums, int nb) {
    __shared__ int s[1024];
    const int tid = threadIdx.x;
    int v = (tid < nb) ? blocksums[tid] : 0;
    s[tid] = v;
    __syncthreads();
    for (int off = 1; off < 1024; off <<= 1) {
        int t = (tid >= off) ? s[tid - off] : 0;
        __syncthreads();
        s[tid] += t;
        __syncthreads();
    }
    if (tid < nb) blocksums[tid] = s[tid] - v;
}

__global__ __launch_bounds__(256) void scan_finalize(int* __restrict__ offsets,
                                                     int* __restrict__ cursor,
                                                     const int* __restrict__ blockoffs,
                                                     int n, int total) {
    int idx = blockIdx.x * blockDim.x + threadIdx.x;
    if (idx < n) {
        int o = offsets[idx] + blockoffs[idx >> 10];
        offsets[idx] = o;
        cursor[idx] = o;
    }
    if (idx == 0) offsets[n] = total;
}

__global__ __launch_bounds__(256) void sort_edges_part(const int* __restrict__ src,
                                                       const int* __restrict__ dst,
                                                       const float* __restrict__ w,
                                                       int* __restrict__ cursor,
                                                       unsigned* __restrict__ pk,
                                                       int E, int span, int M) {
    const int g = blockIdx.x & 7;
    const int rank = blockIdx.x >> 3;
    const int nrank = gridDim.x >> 3;
    const int lo = g * span;
    const int hi = min(lo + span, M);
    for (int e = rank * blockDim.x + threadIdx.x; e < E; e += nrank * blockDim.x) {
        int d = dst[e];
        if (d >= lo && d < hi) {
            int pos = atomicAdd(&cursor[d], 1);
            pk[pos] = ((unsigned)f2h(w[e]) << 16) | (unsigned)src[e];
        }
    }
}

// ---------------- gather1 + relu + WP projection: y4[node] = relu(A_hat h1)[node] @ WP ----------------
// Per wave: one node. Lane owns feats 4l..4l+3; gathers/accumulates in fp32,
// relu, 16 MACs onto WP rows, then 64-lane reduce of 4 outputs. Writes float4.
__global__ __launch_bounds__(256) void gather1_proj(const unsigned short* __restrict__ h,
                                                    const int* __restrict__ offsets,
                                                    const unsigned* __restrict__ pk,
                                                    const float* __restrict__ WP,
                                                    float4* __restrict__ y4, int N) {
    const int lane = threadIdx.x & 63;
    const int wid = threadIdx.x >> 6;
    const int node = blockIdx.x * 4 + wid;
    if (node >= N) return;

    // per-lane WP rows 4l..4l+3 (each 4 floats)
    float wp[4][4];
#pragma unroll
    for (int i = 0; i < 4; ++i) {
        float4 r = ((const float4*)WP)[lane * 4 + i];
        wp[i][0] = r.x; wp[i][1] = r.y; wp[i][2] = r.z; wp[i][3] = r.w;
    }

    const int s0 = offsets[node];
    const int s1 = offsets[node + 1];
    float a0 = 0.f, a1 = 0.f, a2 = 0.f, a3 = 0.f;
    int i = s0;
    for (; i + 4 <= s1; i += 4) {
        unsigned qA = pk[i], qB = pk[i + 1], qC = pk[i + 2], qD = pk[i + 3];
        float wA = h2f(qA >> 16), wB = h2f(qB >> 16), wC = h2f(qC >> 16), wD = h2f(qD >> 16);
        ushort4 vA = ((const ushort4*)(h + (size_t)(qA & 0xffffu) * NHID))[lane];
        ushort4 vB = ((const ushort4*)(h + (size_t)(qB & 0xffffu) * NHID))[lane];
        ushort4 vC = ((const ushort4*)(h + (size_t)(qC & 0xffffu) * NHID))[lane];
        ushort4 vD = ((const ushort4*)(h + (size_t)(qD & 0xffffu) * NHID))[lane];
        a0 += wA * b2f(vA.x) + wB * b2f(vB.x) + wC * b2f(vC.x) + wD * b2f(vD.x);
        a1 += wA * b2f(vA.y) + wB * b2f(vB.y) + wC * b2f(vC.y) + wD * b2f(vD.y);
        a2 += wA * b2f(vA.z) + wB * b2f(vB.z) + wC * b2f(vC.z) + wD * b2f(vD.z);
        a3 += wA * b2f(vA.w) + wB * b2f(vB.w) + wC * b2f(vC.w) + wD * b2f(vD.w);
    }
    for (; i < s1; ++i) {
        unsigned q = pk[i];
        float ww = h2f(q >> 16);
        ushort4 v = ((const ushort4*)(h + (size_t)(q & 0xffffu) * NHID))[lane];
        a0 += ww * b2f(v.x);
        a1 += ww * b2f(v.y);
        a2 += ww * b2f(v.z);
        a3 += ww * b2f(v.w);
    }
    a0 = fmaxf(a0, 0.f); a1 = fmaxf(a1, 0.f);
    a2 = fmaxf(a2, 0.f); a3 = fmaxf(a3, 0.f);

    float t0 = a0 * wp[0][0] + a1 * wp[1][0] + a2 * wp[2][0] + a3 * wp[3][0];
    float t1 = a0 * wp[0][1] + a1 * wp[1][1] + a2 * wp[2][1] + a3 * wp[3][1];
    float t2 = a0 * wp[0][2] + a1 * wp[1][2] + a2 * wp[2][2] + a3 * wp[3][2];
    float t3 = a0 * wp[0][3] + a1 * wp[1][3] + a2 * wp[2][3] + a3 * wp[3][3];
#pragma unroll
    for (int off = 32; off > 0; off >>= 1) {
        t0 += __shfl_down(t0, off);
        t1 += __shfl_down(t1, off);
        t2 += __shfl_down(t2, off);
        t3 += __shfl_down(t3, off);
    }
    if (lane == 0) y4[node] = {t0, t1, t2, t3};
}

// ---------------- gather2 (tiny): za[n], zb[n] = sum_e w_e * y4[src_e] ----------------
// 16 lanes per node (4 nodes/wave, 16 nodes/block). y4 is 800 KB -> L2-hot.
__global__ __launch_bounds__(256) void gather2_small(const float4* __restrict__ y4,
                                                     const int* __restrict__ offsets,
                                                     const unsigned* __restrict__ pk,
                                                     float2* __restrict__ za,
                                                     float2* __restrict__ zb, int N) {
    const int lane = threadIdx.x & 63;
    const int wid = threadIdx.x >> 6;
    const int grp = lane >> 4;          // 0..3
    const int slot = lane & 15;
    const int node = blockIdx.x * 16 + wid * 4 + grp;
    if (node >= N) return;

    const int s0 = offsets[node];
    const int s1 = offsets[node + 1];
    float x0 = 0.f, x1 = 0.f, x2 = 0.f, x3 = 0.f;
    for (int i = s0 + slot; i < s1; i += 16) {
        unsigned q = pk[i];
        float ww = h2f(q >> 16);
        float4 v = y4[q & 0xffffu];
        x0 += ww * v.x; x1 += ww * v.y; x2 += ww * v.z; x3 += ww * v.w;
    }
#pragma unroll
    for (int off = 8; off > 0; off >>= 1) {
        x0 += __shfl_xor(x0, off);
        x1 += __shfl_xor(x1, off);
        x2 += __shfl_xor(x2, off);
        x3 += __shfl_xor(x3, off);
    }
    if (slot == 0) {
        za[node] = {x0, x1};
        zb[node] = {x2, x3};
    }
}

// ---------------- Decode: out[p] = za[ps[p]] + zb[pd[p]] ----------------
__global__ __launch_bounds__(256) void decode_pairs(const float2* __restrict__ za,
                                                    const float2* __restrict__ zb,
                                                    const int* __restrict__ ps,
                                                    const int* __restrict__ pd,
                                                    float2* __restrict__ out, int P) {
    int p = blockIdx.x * blockDim.x + threadIdx.x;
    if (p < P) {
        float2 va = za[ps[p]];
        float2 vb = zb[pd[p]];
        out[p] = {va.x + vb.x, va.y + vb.y};
    }
}

// ================= fp32 fallback path (ws too small or M > 65535) =================
template <bool RELU>
__global__ __launch_bounds__(256) void gemm_tiled(const float* __restrict__ A,
                                                  const float* __restrict__ B,
                                                  float* __restrict__ C,
                                                  int M, int N, int K) {
    __shared__ float As[16][65];
    __shared__ float Bs[16][64];
    const int block_row = blockIdx.x * 64;
    const int block_col = blockIdx.y * 64;
    const int tid = threadIdx.x;
    const int tx = tid & 15;
    const int ty = tid >> 4;
    float c[4][4] = {};
    for (int k0 = 0; k0 < K; k0 += 16) {
#pragma unroll
        for (int i = 0; i < 4; ++i) {
            int idx = tid + i * 256;
            int kk = idx & 15;
            int m = idx >> 4;
            int row = block_row + m;
            float v = 0.f;
            if (row < M) v = A[(long)row * K + k0 + kk];
            if (RELU) v = fmaxf(v, 0.f);
            As[kk][m] = v;
        }
#pragma unroll
        for (int i = 0; i < 4; ++i) {
            int idx = tid + i * 256;
            int n = idx & 63;
            int kk = idx >> 6;
            Bs[kk][n] = B[(long)(k0 + kk) * N + block_col + n];
        }
        __syncthreads();
#pragma unroll
        for (int kk = 0; kk < 16; ++kk) {
            float a[4], b[4];
#pragma unroll
            for (int i = 0; i < 4; ++i) a[i] = As[kk][ty * 4 + i];
#pragma unroll
            for (int j = 0; j < 4; ++j) b[j] = Bs[kk][tx * 4 + j];
#pragma unroll
            for (int i = 0; i < 4; ++i)
#pragma unroll
                for (int j = 0; j < 4; ++j) c[i][j] += a[i] * b[j];
        }
        __syncthreads();
    }
#pragma unroll
    for (int i = 0; i < 4; ++i) {
        int row = block_row + ty * 4 + i;
        if (row < M) {
            float* cp = C + (long)row * N + block_col + tx * 4;
#pragma unroll
            for (int j = 0; j < 4; ++j) cp[j] = c[i][j];
        }
    }
}

__global__ __launch_bounds__(256) void scatter_conv(const float* __restrict__ h,
                                                    const int* __restrict__ src,
                                                    const int* __restrict__ dst,
                                                    const float* __restrict__ w,
                                                    float* __restrict__ z, int E) {
    const int lane = threadIdx.x & 63;
    const int wid = threadIdx.x >> 6;
    const int nwaves = (gridDim.x * blockDim.x) >> 6;
    for (int e = blockIdx.x * 4 + wid; e < E; e += nwaves) {
        int s = src[e];
        int d = dst[e];
        float ww = w[e];
        float4 v = ((const float4*)(h + (long)s * NHID))[lane];
        float* zp = z + (long)d * NHID + lane * 4;
        atomicAdd(zp + 0, ww * v.x);
        atomicAdd(zp + 1, ww * v.y);
        atomicAdd(zp + 2, ww * v.z);
        atomicAdd(zp + 3, ww * v.w);
    }
}

__global__ __launch_bounds__(256) void decode_f(const float* __restrict__ z,
                                                const int* __restrict__ ps,
                                                const int* __restrict__ pd,
                                                const float* __restrict__ Wlin,
                                                float* __restrict__ out, int P) {
    const int lane = threadIdx.x & 63;
    const int wid = threadIdx.x >> 6;
    const int nwaves = (gridDim.x * blockDim.x) >> 6;
    float wa[8], wb[8];
#pragma unroll
    for (int i = 0; i < 8; ++i) {
        wa[i] = Wlin[(lane * 4) * 2 + i];
        wb[i] = Wlin[(NHID + lane * 4) * 2 + i];
    }
    for (int p = blockIdx.x * 4 + wid; p < P; p += nwaves) {
        int a = ps[p];
        int b = pd[p];
        float4 va = ((const float4*)(z + (long)a * NHID))[lane];
        float4 vb = ((const float4*)(z + (long)b * NHID))[lane];
        float acc0 = va.x * wa[0] + va.y * wa[2] + va.z * wa[4] + va.w * wa[6]
                   + vb.x * wb[0] + vb.y * wb[2] + vb.z * wb[4] + vb.w * wb[6];
        float acc1 = va.x * wa[1] + va.y * wa[3] + va.z * wa[5] + va.w * wa[7]
                   + vb.x * wb[1] + vb.y * wb[3] + vb.z * wb[5] + vb.w * wb[7];
#pragma unroll
        for (int off = 32; off > 0; off >>= 1) {
            acc0 += __shfl_down(acc0, off);
            acc1 += __shfl_down(acc1, off);
        }
        if (lane == 0) {
            out[(long)p * 2 + 0] = acc0;
            out[(long)p * 2 + 1] = acc1;
        }
    }
}

extern "C" void kernel_launch(void* const* d_in, const int* in_sizes, int n_in,
                              void* d_out, int out_size, void* d_ws, size_t ws_size,
                              hipStream_t stream) {
    (void)n_in; (void)out_size;
    const float* x    = (const float*)d_in[0];   // [M, 512]
    const int*   ei   = (const int*)d_in[1];     // [2, E]
    const float* ew   = (const float*)d_in[2];   // [E]
    const int*   pei  = (const int*)d_in[3];     // [2, P]
    const float* W1   = (const float*)d_in[4];   // [512, 256]
    const float* W2   = (const float*)d_in[5];   // [256, 256]
    const float* Wlin = (const float*)d_in[6];   // [512, 2]
    float* out = (float*)d_out;                  // [P, 2]

    const int E = in_sizes[2];
    const int P = in_sizes[3] / 2;
    const int M = in_sizes[0] / NFEAT;

    dim3 blk(256);
    const int* src = ei;
    const int* dst = ei + E;

    // workspace layout
    unsigned short* hA = (unsigned short*)d_ws;               // [M,256] bf16 (h1)
    unsigned short* hB = hA + (size_t)M * NHID;               // reused as y4 [M] float4
    int* offsets = (int*)(hB + (size_t)M * NHID);             // [M+1]
    int* cursor  = offsets + (M + 1);                          // [M]
    unsigned* pk = (unsigned*)(cursor + M);                    // [E]
    int* blocksums = (int*)(pk + E);                           // [1024]
    float2* za = (float2*)(blocksums + 1024);                  // [M]
    float2* zb = za + M;                                       // [M]
    const size_t need = 2 * (size_t)M * NHID * 2 + ((size_t)2 * M + 1) * 4
                      + (size_t)E * 4 + 1024 * 4 + (size_t)M * 2 * 8;

    if (ws_size >= need && M <= 65535) {
        unsigned short* F1 = (unsigned short*)d_out;          // 256 KB frag buffer
        float* WP = (float*)((char*)d_out + (size_t)NFEAT * NHID * 2);  // [256][4] = 4 KB
        float4* y4 = (float4*)hB;                              // [M] (reuses hB space)

        const int zt = NFEAT * NHID + NHID * 4 + M;
        prep_all<<<(zt + 255) / 256, blk, 0, stream>>>(W1, W2, Wlin, F1, WP, cursor, M);

        // ---- CSR build (XCD-range-partitioned hist + sort) ----
        const int span = (M + 7) / 8;
        const int nb = (M + 1023) / 1024;
        hist_part<<<2048, blk, 0, stream>>>(dst, cursor, E, span, M);
        scan_local<<<nb, 1024, 0, stream>>>(cursor, offsets, blocksums, M);
        scan_sums<<<1, 1024, 0, stream>>>(blocksums, nb);
        scan_finalize<<<(M + 255) / 256, blk, 0, stream>>>(offsets, cursor, blocksums, M, E);
        sort_edges_part<<<2048, blk, 0, stream>>>(src, dst, ew, cursor, pk, E, span, M);

        // ---- Layer 1 ----
        const int g = (M + 63) / 64;
        gemm1_pipe<<<g, blk, 0, stream>>>(x, F1, hA, M);
        // ---- gather1 + relu + fold(W2@Wlin) projection -> y4 ----
        gather1_proj<<<(M + 3) / 4, blk, 0, stream>>>(hA, offsets, pk, WP, y4, M);
        // ---- tiny layer-2 aggregation ----
        gather2_small<<<(M + 15) / 16, blk, 0, stream>>>(y4, offsets, pk, za, zb, M);
        // ---- Decode ----
        decode_pairs<<<(P + 255) / 256, blk, 0, stream>>>(za, zb, pei, pei + P, (float2*)out, P);
    } else {
        // fp32 atomic fallback
        float* bufA = (float*)d_ws;
        float* bufB = bufA + (size_t)M * NHID;
        const size_t zbytes = (size_t)M * NHID * sizeof(float);
        dim3 gemm_grid((M + 63) / 64, NHID / 64);
        gemm_tiled<false><<<gemm_grid, blk, 0, stream>>>(x, W1, bufA, M, NHID, NFEAT);
        hipMemsetAsync(bufB, 0, zbytes, stream);
        scatter_conv<<<2048, blk, 0, stream>>>(bufA, src, dst, ew, bufB, E);
        gemm_tiled<true><<<gemm_grid, blk, 0, stream>>>(bufB, W2, bufA, M, NHID, NHID);
        hipMemsetAsync(bufB, 0, zbytes, stream);
        scatter_conv<<<2048, blk, 0, stream>>>(bufA, src, dst, ew, bufB, E);
        decode_f<<<(P + 3) / 4, blk, 0, stream>>>(bufB, pei, pei + P, Wlin, out, P);
    }
}

// Round 14
// 183.324 us; speedup vs baseline: 1.6168x; 1.1135x over previous
//
#include <hip/hip_runtime.h>

#define NHID 256
#define NFEAT 512

using short8  = __attribute__((ext_vector_type(8))) short;
using float8  = __attribute__((ext_vector_type(8))) float;
using f32x4   = __attribute__((ext_vector_type(4))) float;

__device__ __forceinline__ float b2f(unsigned short u) {
    union { float f; unsigned v; } c;
    c.v = ((unsigned)u) << 16;
    return c.f;
}
__device__ __forceinline__ unsigned short f2b(float f) {
    union { float f; unsigned u; } c;
    c.f = f;
    unsigned r = c.u + 0x7fffu + ((c.u >> 16) & 1u);  // RNE
    return (unsigned short)(r >> 16);
}
__device__ __forceinline__ unsigned short f2h(float f) {
    union { _Float16 h; unsigned short u; } c;
    c.h = (_Float16)f;
    return c.u;
}
__device__ __forceinline__ float h2f(unsigned short u) {
    union { _Float16 h; unsigned short u; } c;
    c.u = u;
    return (float)c.h;
}

// async global->LDS, 16 B/lane; lds base wave-uniform, gsrc per-lane.
__device__ __forceinline__ void gload16(const void* gsrc, void* lds) {
    __builtin_amdgcn_global_load_lds((const __attribute__((address_space(1))) unsigned int*)gsrc,
                                     (__attribute__((address_space(3))) unsigned int*)lds,
                                     16, 0, 0);
}

// ---------------- prep: W1 -> MFMA frags, WP = W2 @ [Wlin_top|Wlin_bot], cursor zero ----------------
__global__ __launch_bounds__(256) void prep_all(const float* __restrict__ W1,
                                                const float* __restrict__ W2,
                                                const float* __restrict__ Wlin,
                                                unsigned short* __restrict__ F1,
                                                float* __restrict__ WP,
                                                int* __restrict__ cursor, int M) {
    int i = blockIdx.x * blockDim.x + threadIdx.x;
    const int T1 = NFEAT * NHID;   // 131072
    if (i < T1) {
        int j = i & 7, l = (i >> 3) & 63, cb = (i >> 9) & 15, t = i >> 13;
        int n = cb * 16 + (l & 15);
        int k = t * 32 + ((l >> 4) << 3) + j;
        F1[i] = f2b(W1[k * NHID + n]);
    } else if (i < T1 + NHID * 4) {
        int i3 = i - T1;
        int k = i3 >> 2, j = i3 & 3;
        const int base = (j >= 2) ? NHID : 0;
        const int col = j & 1;
        float acc = 0.f;
        for (int n = 0; n < NHID; ++n)
            acc += W2[k * NHID + n] * Wlin[(base + n) * 2 + col];
        WP[k * 4 + j] = acc;
    } else {
        int j = i - T1 - NHID * 4;
        if (j < M) cursor[j] = 0;
    }
}

// ---------------- GEMM1 body: 64 rows x 256 cols, A in LDS (2-buf, gload), B in regs ----------------
__device__ __forceinline__ void gemm1_body(const float* __restrict__ x,
                                           const unsigned short* __restrict__ F1,
                                           unsigned short* __restrict__ C, int M,
                                           int brow, char* AsRaw) {
    const int tid = threadIdx.x;
    const int lane = tid & 63;
    const int wc = tid >> 6;
    const int lrow = lane & 15;
    const int lq = lane >> 4;
    const int nt = NFEAT / 32;   // 16

    int ar0 = brow + wc * 16 + (lane >> 3);
    int ar1 = ar0 + 8;
    if (ar0 >= M) ar0 = M - 1;
    if (ar1 >= M) ar1 = M - 1;
    const int aswz = ((lane & 7) ^ (lane >> 3)) * 4;   // fp32 elems within 32-wide slice
    const float* ag0 = x + (size_t)ar0 * NFEAT + aswz;
    const float* ag1 = x + (size_t)ar1 * NFEAT + aswz;
    const unsigned short* bsrc = F1 + (wc * 4) * 512 + lane * 8;

    f32x4 acc[4][4] = {};

    // prologue: stage A tile 0, load B tile 0 to regs
    gload16(ag0, AsRaw + wc * 2048);
    gload16(ag1, AsRaw + wc * 2048 + 1024);
    short8 bc0 = *(const short8*)(bsrc + 0 * 512);
    short8 bc1 = *(const short8*)(bsrc + 1 * 512);
    short8 bc2 = *(const short8*)(bsrc + 2 * 512);
    short8 bc3 = *(const short8*)(bsrc + 3 * 512);
    __syncthreads();

    int p = 0;
#pragma unroll
    for (int t = 0; t < 16; ++t) {
        short8 bn0, bn1, bn2, bn3;
        if (t + 1 < nt) {
            // prefetch next A tile into other LDS buffer + next B into regs
            gload16(ag0 + (t + 1) * 32, AsRaw + (p ^ 1) * 8192 + wc * 2048);
            gload16(ag1 + (t + 1) * 32, AsRaw + (p ^ 1) * 8192 + wc * 2048 + 1024);
            const unsigned short* bs_ = bsrc + (t + 1) * 8192;
            bn0 = *(const short8*)(bs_ + 0 * 512);
            bn1 = *(const short8*)(bs_ + 1 * 512);
            bn2 = *(const short8*)(bs_ + 2 * 512);
            bn3 = *(const short8*)(bs_ + 3 * 512);
        }
        // A from LDS (XOR-swizzled) + convert
        short8 a[4];
#pragma unroll
        for (int m = 0; m < 4; ++m) {
            int row = m * 16 + lrow;
            const char* base = AsRaw + p * 8192 + row * 128;
            int sw = (row & 7) << 4;
            float4 f0 = *(const float4*)(base + ((lq * 32) ^ sw));
            float4 f1 = *(const float4*)(base + ((lq * 32 + 16) ^ sw));
            short8 v;
            v[0] = (short)f2b(f0.x); v[1] = (short)f2b(f0.y);
            v[2] = (short)f2b(f0.z); v[3] = (short)f2b(f0.w);
            v[4] = (short)f2b(f1.x); v[5] = (short)f2b(f1.y);
            v[6] = (short)f2b(f1.z); v[7] = (short)f2b(f1.w);
            a[m] = v;
        }
#pragma unroll
        for (int m = 0; m < 4; ++m) {
            acc[m][0] = __builtin_amdgcn_mfma_f32_16x16x32_bf16(a[m], bc0, acc[m][0], 0, 0, 0);
            acc[m][1] = __builtin_amdgcn_mfma_f32_16x16x32_bf16(a[m], bc1, acc[m][1], 0, 0, 0);
            acc[m][2] = __builtin_amdgcn_mfma_f32_16x16x32_bf16(a[m], bc2, acc[m][2], 0, 0, 0);
            acc[m][3] = __builtin_amdgcn_mfma_f32_16x16x32_bf16(a[m], bc3, acc[m][3], 0, 0, 0);
        }
        __syncthreads();
        p ^= 1;
        bc0 = bn0; bc1 = bn1; bc2 = bn2; bc3 = bn3;
    }

#pragma unroll
    for (int m = 0; m < 4; ++m)
#pragma unroll
        for (int r = 0; r < 4; ++r) {
            int row = brow + m * 16 + (lane >> 4) * 4 + r;
            if (row < M) {
#pragma unroll
                for (int n = 0; n < 4; ++n) {
                    int col = wc * 64 + n * 16 + (lane & 15);
                    C[(size_t)row * NHID + col] = f2b(acc[m][n][r]);
                }
            }
        }
}

// ---------------- fused: gemm1 (first half rows) + hist ----------------
__global__ __launch_bounds__(256) void fused_g1_hist(const float* __restrict__ x,
                                                     const unsigned short* __restrict__ F1,
                                                     unsigned short* __restrict__ C, int M,
                                                     int gblocks,
                                                     const int* __restrict__ dst,
                                                     int* __restrict__ counts,
                                                     int E, int span) {
    __shared__ char AsRaw[2 * 8192];
    if ((int)blockIdx.x < gblocks) {
        gemm1_body(x, F1, C, M, blockIdx.x * 64, AsRaw);
    } else {
        const int rank = blockIdx.x - gblocks;
        const int nrank = gridDim.x - gblocks;
        const int g = rank & 7;
        const int r8 = rank >> 3;
        const int n8 = nrank >> 3;
        const int lo = g * span;
        const int hi = min(lo + span, M);
        for (int e = r8 * blockDim.x + threadIdx.x; e < E; e += n8 * blockDim.x) {
            int d = dst[e];
            if (d >= lo && d < hi) atomicAdd(&counts[d], 1);
        }
    }
}

// ---------------- fused: gemm1 (second half rows) + sort ----------------
__global__ __launch_bounds__(256) void fused_g1_sort(const float* __restrict__ x,
                                                     const unsigned short* __restrict__ F1,
                                                     unsigned short* __restrict__ C, int M,
                                                     int gblocks, int rowbase,
                                                     const int* __restrict__ src,
                                                     const int* __restrict__ dst,
                                                     const float* __restrict__ w,
                                                     int* __restrict__ cursor,
                                                     unsigned* __restrict__ pk,
                                                     int E, int span) {
    __shared__ char AsRaw[2 * 8192];
    if ((int)blockIdx.x < gblocks) {
        gemm1_body(x, F1, C, M, (rowbase + blockIdx.x) * 64, AsRaw);
    } else {
        const int rank = blockIdx.x - gblocks;
        const int nrank = gridDim.x - gblocks;
        const int g = rank & 7;
        const int r8 = rank >> 3;
        const int n8 = nrank >> 3;
        const int lo = g * span;
        const int hi = min(lo + span, M);
        for (int e = r8 * blockDim.x + threadIdx.x; e < E; e += n8 * blockDim.x) {
            int d = dst[e];
            if (d >= lo && d < hi) {
                int pos = atomicAdd(&cursor[d], 1);
                pk[pos] = ((unsigned)f2h(w[e]) << 16) | (unsigned)src[e];
            }
        }
    }
}

// ---------------- scan chain (unchanged) ----------------
__global__ __launch_bounds__(1024) void scan_local(const int* __restrict__ counts,
                                                   int* __restrict__ local,
                                                   int* __restrict__ blocksums, int n) {
    __shared__ int s[1024];
    const int tid = threadIdx.x;
    const int idx = blockIdx.x * 1024 + tid;
    int v = (idx < n) ? counts[idx] : 0;
    s[tid] = v;
    __syncthreads();
    for (int off = 1; off < 1024; off <<= 1) {
        int t = (tid >= off) ? s[tid - off] : 0;
        __syncthreads();
        s[tid] += t;
        __syncthreads();
    }
    if (idx < n) local[idx] = s[tid] - v;
    if (tid == 1023) blocksums[blockIdx.x] = s[1023];
}

__global__ __launch_bounds__(1024) void scan_sums(int* __restrict__ blocksums, int nb) {
    __shared__ int s[1024];
    const int tid = threadIdx.x;
    int v = (tid < nb) ? blocksums[tid] : 0;
    s[tid] = v;
    __syncthreads();
    for (int off = 1; off < 1024; off <<= 1) {
        int t = (tid >= off) ? s[tid - off] : 0;
        __syncthreads();
        s[tid] += t;
        __syncthreads();
    }
    if (tid < nb) blocksums[tid] = s[tid] - v;
}

__global__ __launch_bounds__(256) void scan_finalize(int* __restrict__ offsets,
                                                     int* __restrict__ cursor,
                                                     const int* __restrict__ blockoffs,
                                                     int n, int total) {
    int idx = blockIdx.x * blockDim.x + threadIdx.x;
    if (idx < n) {
        int o = offsets[idx] + blockoffs[idx >> 10];
        offsets[idx] = o;
        cursor[idx] = o;
    }
    if (idx == 0) offsets[n] = total;
}

// ---------------- gather1 + relu + WP projection (unchanged) ----------------
__global__ __launch_bounds__(256) void gather1_proj(const unsigned short* __restrict__ h,
                                                    const int* __restrict__ offsets,
                                                    const unsigned* __restrict__ pk,
                                                    const float* __restrict__ WP,
                                                    float4* __restrict__ y4, int N) {
    const int lane = threadIdx.x & 63;
    const int wid = threadIdx.x >> 6;
    const int node = blockIdx.x * 4 + wid;
    if (node >= N) return;

    float wp[4][4];
#pragma unroll
    for (int i = 0; i < 4; ++i) {
        float4 r = ((const float4*)WP)[lane * 4 + i];
        wp[i][0] = r.x; wp[i][1] = r.y; wp[i][2] = r.z; wp[i][3] = r.w;
    }

    const int s0 = offsets[node];
    const int s1 = offsets[node + 1];
    float a0 = 0.f, a1 = 0.f, a2 = 0.f, a3 = 0.f;
    int i = s0;
    for (; i + 4 <= s1; i += 4) {
        unsigned qA = pk[i], qB = pk[i + 1], qC = pk[i + 2], qD = pk[i + 3];
        float wA = h2f(qA >> 16), wB = h2f(qB >> 16), wC = h2f(qC >> 16), wD = h2f(qD >> 16);
        ushort4 vA = ((const ushort4*)(h + (size_t)(qA & 0xffffu) * NHID))[lane];
        ushort4 vB = ((const ushort4*)(h + (size_t)(qB & 0xffffu) * NHID))[lane];
        ushort4 vC = ((const ushort4*)(h + (size_t)(qC & 0xffffu) * NHID))[lane];
        ushort4 vD = ((const ushort4*)(h + (size_t)(qD & 0xffffu) * NHID))[lane];
        a0 += wA * b2f(vA.x) + wB * b2f(vB.x) + wC * b2f(vC.x) + wD * b2f(vD.x);
        a1 += wA * b2f(vA.y) + wB * b2f(vB.y) + wC * b2f(vC.y) + wD * b2f(vD.y);
        a2 += wA * b2f(vA.z) + wB * b2f(vB.z) + wC * b2f(vC.z) + wD * b2f(vD.z);
        a3 += wA * b2f(vA.w) + wB * b2f(vB.w) + wC * b2f(vC.w) + wD * b2f(vD.w);
    }
    for (; i < s1; ++i) {
        unsigned q = pk[i];
        float ww = h2f(q >> 16);
        ushort4 v = ((const ushort4*)(h + (size_t)(q & 0xffffu) * NHID))[lane];
        a0 += ww * b2f(v.x);
        a1 += ww * b2f(v.y);
        a2 += ww * b2f(v.z);
        a3 += ww * b2f(v.w);
    }
    a0 = fmaxf(a0, 0.f); a1 = fmaxf(a1, 0.f);
    a2 = fmaxf(a2, 0.f); a3 = fmaxf(a3, 0.f);

    float t0 = a0 * wp[0][0] + a1 * wp[1][0] + a2 * wp[2][0] + a3 * wp[3][0];
    float t1 = a0 * wp[0][1] + a1 * wp[1][1] + a2 * wp[2][1] + a3 * wp[3][1];
    float t2 = a0 * wp[0][2] + a1 * wp[1][2] + a2 * wp[2][2] + a3 * wp[3][2];
    float t3 = a0 * wp[0][3] + a1 * wp[1][3] + a2 * wp[2][3] + a3 * wp[3][3];
#pragma unroll
    for (int off = 32; off > 0; off >>= 1) {
        t0 += __shfl_down(t0, off);
        t1 += __shfl_down(t1, off);
        t2 += __shfl_down(t2, off);
        t3 += __shfl_down(t3, off);
    }
    if (lane == 0) y4[node] = {t0, t1, t2, t3};
}

// ---------------- gather2 (tiny, unchanged) ----------------
__global__ __launch_bounds__(256) void gather2_small(const float4* __restrict__ y4,
                                                     const int* __restrict__ offsets,
                                                     const unsigned* __restrict__ pk,
                                                     float2* __restrict__ za,
                                                     float2* __restrict__ zb, int N) {
    const int lane = threadIdx.x & 63;
    const int wid = threadIdx.x >> 6;
    const int grp = lane >> 4;
    const int slot = lane & 15;
    const int node = blockIdx.x * 16 + wid * 4 + grp;
    if (node >= N) return;

    const int s0 = offsets[node];
    const int s1 = offsets[node + 1];
    float x0 = 0.f, x1 = 0.f, x2 = 0.f, x3 = 0.f;
    for (int i = s0 + slot; i < s1; i += 16) {
        unsigned q = pk[i];
        float ww = h2f(q >> 16);
        float4 v = y4[q & 0xffffu];
        x0 += ww * v.x; x1 += ww * v.y; x2 += ww * v.z; x3 += ww * v.w;
    }
#pragma unroll
    for (int off = 8; off > 0; off >>= 1) {
        x0 += __shfl_xor(x0, off);
        x1 += __shfl_xor(x1, off);
        x2 += __shfl_xor(x2, off);
        x3 += __shfl_xor(x3, off);
    }
    if (slot == 0) {
        za[node] = {x0, x1};
        zb[node] = {x2, x3};
    }
}

// ---------------- Decode (unchanged) ----------------
__global__ __launch_bounds__(256) void decode_pairs(const float2* __restrict__ za,
                                                    const float2* __restrict__ zb,
                                                    const int* __restrict__ ps,
                                                    const int* __restrict__ pd,
                                                    float2* __restrict__ out, int P) {
    int p = blockIdx.x * blockDim.x + threadIdx.x;
    if (p < P) {
        float2 va = za[ps[p]];
        float2 vb = zb[pd[p]];
        out[p] = {va.x + vb.x, va.y + vb.y};
    }
}

// ================= fp32 fallback path (ws too small or M > 65535) =================
template <bool RELU>
__global__ __launch_bounds__(256) void gemm_tiled(const float* __restrict__ A,
                                                  const float* __restrict__ B,
                                                  float* __restrict__ C,
                                                  int M, int N, int K) {
    __shared__ float As[16][65];
    __shared__ float Bs[16][64];
    const int block_row = blockIdx.x * 64;
    const int block_col = blockIdx.y * 64;
    const int tid = threadIdx.x;
    const int tx = tid & 15;
    const int ty = tid >> 4;
    float c[4][4] = {};
    for (int k0 = 0; k0 < K; k0 += 16) {
#pragma unroll
        for (int i = 0; i < 4; ++i) {
            int idx = tid + i * 256;
            int kk = idx & 15;
            int m = idx >> 4;
            int row = block_row + m;
            float v = 0.f;
            if (row < M) v = A[(long)row * K + k0 + kk];
            if (RELU) v = fmaxf(v, 0.f);
            As[kk][m] = v;
        }
#pragma unroll
        for (int i = 0; i < 4; ++i) {
            int idx = tid + i * 256;
            int n = idx & 63;
            int kk = idx >> 6;
            Bs[kk][n] = B[(long)(k0 + kk) * N + block_col + n];
        }
        __syncthreads();
#pragma unroll
        for (int kk = 0; kk < 16; ++kk) {
            float a[4], b[4];
#pragma unroll
            for (int i = 0; i < 4; ++i) a[i] = As[kk][ty * 4 + i];
#pragma unroll
            for (int j = 0; j < 4; ++j) b[j] = Bs[kk][tx * 4 + j];
#pragma unroll
            for (int i = 0; i < 4; ++i)
#pragma unroll
                for (int j = 0; j < 4; ++j) c[i][j] += a[i] * b[j];
        }
        __syncthreads();
    }
#pragma unroll
    for (int i = 0; i < 4; ++i) {
        int row = block_row + ty * 4 + i;
        if (row < M) {
            float* cp = C + (long)row * N + block_col + tx * 4;
#pragma unroll
            for (int j = 0; j < 4; ++j) cp[j] = c[i][j];
        }
    }
}

__global__ __launch_bounds__(256) void scatter_conv(const float* __restrict__ h,
                                                    const int* __restrict__ src,
                                                    const int* __restrict__ dst,
                                                    const float* __restrict__ w,
                                                    float* __restrict__ z, int E) {
    const int lane = threadIdx.x & 63;
    const int wid = threadIdx.x >> 6;
    const int nwaves = (gridDim.x * blockDim.x) >> 6;
    for (int e = blockIdx.x * 4 + wid; e < E; e += nwaves) {
        int s = src[e];
        int d = dst[e];
        float ww = w[e];
        float4 v = ((const float4*)(h + (long)s * NHID))[lane];
        float* zp = z + (long)d * NHID + lane * 4;
        atomicAdd(zp + 0, ww * v.x);
        atomicAdd(zp + 1, ww * v.y);
        atomicAdd(zp + 2, ww * v.z);
        atomicAdd(zp + 3, ww * v.w);
    }
}

__global__ __launch_bounds__(256) void decode_f(const float* __restrict__ z,
                                                const int* __restrict__ ps,
                                                const int* __restrict__ pd,
                                                const float* __restrict__ Wlin,
                                                float* __restrict__ out, int P) {
    const int lane = threadIdx.x & 63;
    const int wid = threadIdx.x >> 6;
    const int nwaves = (gridDim.x * blockDim.x) >> 6;
    float wa[8], wb[8];
#pragma unroll
    for (int i = 0; i < 8; ++i) {
        wa[i] = Wlin[(lane * 4) * 2 + i];
        wb[i] = Wlin[(NHID + lane * 4) * 2 + i];
    }
    for (int p = blockIdx.x * 4 + wid; p < P; p += nwaves) {
        int a = ps[p];
        int b = pd[p];
        float4 va = ((const float4*)(z + (long)a * NHID))[lane];
        float4 vb = ((const float4*)(z + (long)b * NHID))[lane];
        float acc0 = va.x * wa[0] + va.y * wa[2] + va.z * wa[4] + va.w * wa[6]
                   + vb.x * wb[0] + vb.y * wb[2] + vb.z * wb[4] + vb.w * wb[6];
        float acc1 = va.x * wa[1] + va.y * wa[3] + va.z * wa[5] + va.w * wa[7]
                   + vb.x * wb[1] + vb.y * wb[3] + vb.z * wb[5] + vb.w * wb[7];
#pragma unroll
        for (int off = 32; off > 0; off >>= 1) {
            acc0 += __shfl_down(acc0, off);
            acc1 += __shfl_down(acc1, off);
        }
        if (lane == 0) {
            out[(long)p * 2 + 0] = acc0;
            out[(long)p * 2 + 1] = acc1;
        }
    }
}

extern "C" void kernel_launch(void* const* d_in, const int* in_sizes, int n_in,
                              void* d_out, int out_size, void* d_ws, size_t ws_size,
                              hipStream_t stream) {
    (void)n_in; (void)out_size;
    const float* x    = (const float*)d_in[0];   // [M, 512]
    const int*   ei   = (const int*)d_in[1];     // [2, E]
    const float* ew   = (const float*)d_in[2];   // [E]
    const int*   pei  = (const int*)d_in[3];     // [2, P]
    const float* W1   = (const float*)d_in[4];   // [512, 256]
    const float* W2   = (const float*)d_in[5];   // [256, 256]
    const float* Wlin = (const float*)d_in[6];   // [512, 2]
    float* out = (float*)d_out;                  // [P, 2]

    const int E = in_sizes[2];
    const int P = in_sizes[3] / 2;
    const int M = in_sizes[0] / NFEAT;

    dim3 blk(256);
    const int* src = ei;
    const int* dst = ei + E;

    // workspace layout
    unsigned short* hA = (unsigned short*)d_ws;               // [M,256] bf16 (h1)
    unsigned short* hB = hA + (size_t)M * NHID;               // reused as y4 [M] float4
    int* offsets = (int*)(hB + (size_t)M * NHID);             // [M+1]
    int* cursor  = offsets + (M + 1);                          // [M]
    unsigned* pk = (unsigned*)(cursor + M);                    // [E]
    int* blocksums = (int*)(pk + E);                           // [1024]
    float2* za = (float2*)(blocksums + 1024);                  // [M]
    float2* zb = za + M;                                       // [M]
    const size_t need = 2 * (size_t)M * NHID * 2 + ((size_t)2 * M + 1) * 4
                      + (size_t)E * 4 + 1024 * 4 + (size_t)M * 2 * 8;

    if (ws_size >= need && M <= 65535) {
        unsigned short* F1 = (unsigned short*)d_out;          // 256 KB frag buffer
        float* WP = (float*)((char*)d_out + (size_t)NFEAT * NHID * 2);  // 4 KB
        float4* y4 = (float4*)hB;

        const int zt = NFEAT * NHID + NHID * 4 + M;
        prep_all<<<(zt + 255) / 256, blk, 0, stream>>>(W1, W2, Wlin, F1, WP, cursor, M);

        const int span = (M + 7) / 8;
        const int nb = (M + 1023) / 1024;
        const int g = (M + 63) / 64;       // total gemm1 blocks
        const int g1 = g / 2;              // first half rows
        const int g2 = g - g1;
        const int CSRB = 1024;             // csr blocks per fused launch

        // ---- K2: gemm1 rows [0, g1*64) fused with hist ----
        fused_g1_hist<<<g1 + CSRB, blk, 0, stream>>>(x, F1, hA, M, g1, dst, cursor, E, span);
        // ---- scan chain ----
        scan_local<<<nb, 1024, 0, stream>>>(cursor, offsets, blocksums, M);
        scan_sums<<<1, 1024, 0, stream>>>(blocksums, nb);
        scan_finalize<<<(M + 255) / 256, blk, 0, stream>>>(offsets, cursor, blocksums, M, E);
        // ---- K6: gemm1 rows [g1*64, M) fused with sort ----
        fused_g1_sort<<<g2 + CSRB, blk, 0, stream>>>(x, F1, hA, M, g2, g1,
                                                     src, dst, ew, cursor, pk, E, span);
        // ---- gather1 + relu + WP projection -> y4 ----
        gather1_proj<<<(M + 3) / 4, blk, 0, stream>>>(hA, offsets, pk, WP, y4, M);
        // ---- tiny layer-2 aggregation ----
        gather2_small<<<(M + 15) / 16, blk, 0, stream>>>(y4, offsets, pk, za, zb, M);
        // ---- Decode ----
        decode_pairs<<<(P + 255) / 256, blk, 0, stream>>>(za, zb, pei, pei + P, (float2*)out, P);
    } else {
        // fp32 atomic fallback
        float* bufA = (float*)d_ws;
        float* bufB = bufA + (size_t)M * NHID;
        const size_t zbytes = (size_t)M * NHID * sizeof(float);
        dim3 gemm_grid((M + 63) / 64, NHID / 64);
        gemm_tiled<false><<<gemm_grid, blk, 0, stream>>>(x, W1, bufA, M, NHID, NFEAT);
        hipMemsetAsync(bufB, 0, zbytes, stream);
        scatter_conv<<<2048, blk, 0, stream>>>(bufA, src, dst, ew, bufB, E);
        gemm_tiled<true><<<gemm_grid, blk, 0, stream>>>(bufB, W2, bufA, M, NHID, NHID);
        hipMemsetAsync(bufB, 0, zbytes, stream);
        scatter_conv<<<2048, blk, 0, stream>>>(bufA, src, dst, ew, bufB, E);
        decode_f<<<(P + 3) / 4, blk, 0, stream>>>(bufB, pei, pei + P, Wlin, out, P);
    }
}